// Round 1
// baseline (274.810 us; speedup 1.0000x reference)
//
#include <hip/hip_runtime.h>

typedef __attribute__((ext_vector_type(8))) short short8;
typedef __attribute__((ext_vector_type(4))) float float4v;
typedef __attribute__((ext_vector_type(4))) float floatx4;
typedef __attribute__((ext_vector_type(4))) unsigned short ushort4v;

#define DEV static __device__ __forceinline__

DEV unsigned short f2bf(float f){
  unsigned u = __builtin_bit_cast(unsigned, f);
  unsigned r = u + 0x7FFFu + ((u >> 16) & 1u);
  return (unsigned short)(r >> 16);
}
DEV float bf2f(unsigned short h){
  unsigned u = ((unsigned)h) << 16;
  return __builtin_bit_cast(float, u);
}
DEV float softplus_f(float x){
  if (x > 20.f) return x;
  return log1pf(expf(x));
}

// ---------------------------------------------------------------------------
// fw = reverse cumsum of softplus(freq_raw); pw = softplus(sym(pool_raw))
__global__ void k_prep_fw(const float* __restrict__ freq_raw,
                          const float* __restrict__ pool_raw,
                          float* __restrict__ fw, float* __restrict__ pw){
  __shared__ float s[1024];
  int d = threadIdx.x;
  s[d] = softplus_f(freq_raw[d]);
  __syncthreads();
  for (int off = 1; off < 1024; off <<= 1){
    float t = (d + off < 1024) ? s[d + off] : 0.f;
    __syncthreads();
    s[d] += t;
    __syncthreads();
  }
  fw[d] = s[d];
  if (d < 3) pw[d] = softplus_f((pool_raw[d] + pool_raw[2 - d]) * 0.5f);
}

// ---------------------------------------------------------------------------
// Build W~q = fw[n]*W_q (hi/lo bf16 split), W~k = conv3(W_k rows) (hi/lo),
// and plain bf16 W_v, W_o.
__global__ __launch_bounds__(256) void k_prep_w(
    const float* __restrict__ Wq, const float* __restrict__ Wk,
    const float* __restrict__ Wv, const float* __restrict__ Wo,
    const float* __restrict__ fw, const float* __restrict__ pw,
    unsigned short* __restrict__ wq_h, unsigned short* __restrict__ wq_l,
    unsigned short* __restrict__ wk_h, unsigned short* __restrict__ wk_l,
    unsigned short* __restrict__ wv_b, unsigned short* __restrict__ wo_b){
  int idx = blockIdx.x * 256 + threadIdx.x;      // 0..262143
  int n  = idx >> 8;
  int k4 = (idx & 255) << 2;
  float p0 = pw[0], p1 = pw[1], p2 = pw[2];
  float f = fw[n];
  int o = n * 1024 + k4;
  float4v q4 = *(const float4v*)(Wq + o);
  float4v k0v = *(const float4v*)(Wk + o);
  float4v km = {0.f,0.f,0.f,0.f}, kp = {0.f,0.f,0.f,0.f};
  if (n > 0)    km = *(const float4v*)(Wk + o - 1024);
  if (n < 1023) kp = *(const float4v*)(Wk + o + 1024);
  float4v v4 = *(const float4v*)(Wv + o);
  float4v o4 = *(const float4v*)(Wo + o);
  ushort4v qh, ql, kh, kl, vb, ob;
  for (int j = 0; j < 4; j++){
    float wq_ = f * q4[j];
    unsigned short h = f2bf(wq_);
    qh[j] = h; ql[j] = f2bf(wq_ - bf2f(h));
    float wk_ = p0 * km[j] + p1 * k0v[j] + p2 * kp[j];
    h = f2bf(wk_);
    kh[j] = h; kl[j] = f2bf(wk_ - bf2f(h));
    vb[j] = f2bf(v4[j]);
    ob[j] = f2bf(o4[j]);
  }
  *(ushort4v*)(wq_h + o) = qh; *(ushort4v*)(wq_l + o) = ql;
  *(ushort4v*)(wk_h + o) = kh; *(ushort4v*)(wk_l + o) = kl;
  *(ushort4v*)(wv_b + o) = vb; *(ushort4v*)(wo_b + o) = ob;
}

// ---------------------------------------------------------------------------
// Split x (fp32) into bf16 hi/lo
__global__ __launch_bounds__(256) void k_split_x(const float* __restrict__ x,
                                                 unsigned short* __restrict__ xh,
                                                 unsigned short* __restrict__ xl){
  int idx = blockIdx.x * 256 + threadIdx.x;
  int o = idx * 4;
  float4v v = *(const float4v*)(x + o);
  ushort4v h4, l4;
  for (int j = 0; j < 4; j++){
    unsigned short h = f2bf(v[j]);
    h4[j] = h; l4[j] = f2bf(v[j] - bf2f(h));
  }
  *(ushort4v*)(xh + o) = h4;
  *(ushort4v*)(xl + o) = l4;
}

// ---------------------------------------------------------------------------
// GEMM: C[M,N] = A[M,K] @ B[N,K]^T. 128x128 tile, BK=32, 4 waves (2x2 of 64x64).
// SPLIT: A,B given as hi+lo bf16, 3 MFMAs per fragment (drop lo*lo).
// OUT: 0 = write bf16 hi/lo pair, 1 = write bf16, 2 = write fp32.
template<int SPLIT, int OUT>
__global__ __launch_bounds__(256) void k_gemm(
    const unsigned short* __restrict__ Ah, const unsigned short* __restrict__ Al,
    const unsigned short* __restrict__ Bh, const unsigned short* __restrict__ Bl,
    void* __restrict__ out0, unsigned short* __restrict__ out1,
    int M, int N, int K){
  constexpr int NT = SPLIT ? 4 : 2;
  __shared__ unsigned short lds[NT * 4096];
  unsigned short* sAh = lds;
  unsigned short* sAl = SPLIT ? lds + 4096 : nullptr;
  unsigned short* sBh = lds + (SPLIT ? 2 : 1) * 4096;
  unsigned short* sBl = SPLIT ? lds + 3 * 4096 : nullptr;

  int tid = threadIdx.x;
  int w = tid >> 6, l = tid & 63, lg = l >> 4, lr = l & 15;
  int wr = w >> 1, wc = w & 1;
  int n0 = blockIdx.x * 128, m0 = blockIdx.y * 128;

  floatx4 acc[4][4] = {};

  for (int kt = 0; kt < K; kt += 32){
    if (kt) __syncthreads();
    for (int rep = 0; rep < 2; rep++){
      int idx = rep * 256 + tid;        // 0..511 chunks of 16B
      int r = idx >> 2, c = idx & 3;    // row 0..127, 16B-chunk 0..3
      int dst = r * 32 + ((((c * 16) ^ ((r & 3) << 4))) >> 1);
      int srcA = (m0 + r) * K + kt + c * 8;
      int srcB = (n0 + r) * K + kt + c * 8;
      *(short8*)(sAh + dst) = *(const short8*)(Ah + srcA);
      *(short8*)(sBh + dst) = *(const short8*)(Bh + srcB);
      if (SPLIT){
        *(short8*)(sAl + dst) = *(const short8*)(Al + srcA);
        *(short8*)(sBl + dst) = *(const short8*)(Bl + srcB);
      }
    }
    __syncthreads();
    short8 a_h[4], a_l[4], b_h[4], b_l[4];
    for (int ms = 0; ms < 4; ms++){
      int r = wr * 64 + ms * 16 + lr;
      int off = r * 32 + ((((lg * 16) ^ ((r & 3) << 4))) >> 1);
      a_h[ms] = *(const short8*)(sAh + off);
      if (SPLIT) a_l[ms] = *(const short8*)(sAl + off);
    }
    for (int ns = 0; ns < 4; ns++){
      int r = wc * 64 + ns * 16 + lr;
      int off = r * 32 + ((((lg * 16) ^ ((r & 3) << 4))) >> 1);
      b_h[ns] = *(const short8*)(sBh + off);
      if (SPLIT) b_l[ns] = *(const short8*)(sBl + off);
    }
    for (int ms = 0; ms < 4; ms++)
      for (int ns = 0; ns < 4; ns++){
        acc[ms][ns] = __builtin_amdgcn_mfma_f32_16x16x32_bf16(a_h[ms], b_h[ns], acc[ms][ns], 0, 0, 0);
        if (SPLIT){
          acc[ms][ns] = __builtin_amdgcn_mfma_f32_16x16x32_bf16(a_h[ms], b_l[ns], acc[ms][ns], 0, 0, 0);
          acc[ms][ns] = __builtin_amdgcn_mfma_f32_16x16x32_bf16(a_l[ms], b_h[ns], acc[ms][ns], 0, 0, 0);
        }
      }
  }
  for (int ms = 0; ms < 4; ms++)
    for (int ns = 0; ns < 4; ns++){
      int mrow = m0 + wr * 64 + ms * 16 + lg * 4;
      int ncol = n0 + wc * 64 + ns * 16 + lr;
      for (int rr = 0; rr < 4; rr++){
        float v = acc[ms][ns][rr];
        int o = (mrow + rr) * N + ncol;
        if (OUT == 0){
          unsigned short h = f2bf(v);
          ((unsigned short*)out0)[o] = h;
          out1[o] = f2bf(v - bf2f(h));
        } else if (OUT == 1){
          ((unsigned short*)out0)[o] = f2bf(v);
        } else {
          ((float*)out0)[o] = v;
        }
      }
    }
}

// ---------------------------------------------------------------------------
// Transpose V [B*S, H*hd] (bf16) -> Vt [B,H,hd,S]
__global__ __launch_bounds__(256) void k_transpose(const unsigned short* __restrict__ V,
                                                   unsigned short* __restrict__ Vt){
  __shared__ unsigned short t[64][72];
  int tid = threadIdx.x;
  int gx = blockIdx.x;
  int st = gx & 15, bh = gx >> 4;
  int b = bh >> 4, h = bh & 15;
  int s0 = st * 64;
  for (int idx = tid; idx < 512; idx += 256){
    int i = idx >> 3, c = idx & 7;
    short8 v = *(const short8*)(V + (b * 1024 + s0 + i) * 1024 + h * 64 + c * 8);
    *(short8*)(&t[i][c * 8]) = v;
  }
  __syncthreads();
  for (int idx = tid; idx < 512; idx += 256){
    int j = idx >> 3, ci = idx & 7;
    short8 o;
    for (int ii = 0; ii < 8; ii++) o[ii] = (short)t[ci * 8 + ii][j];
    *(short8*)(Vt + (bh * 64 + j) * 1024 + s0 + ci * 8) = o;
  }
}

// ---------------------------------------------------------------------------
// Flash attention. Grid: 1024 = (b,h) * 16 q-tiles. 4 waves x 16 q-rows.
// K-tiles of 64; QK^T uses split-3x bf16 (hi/lo), PV plain bf16.
__global__ __launch_bounds__(256) void k_attn(
    const unsigned short* __restrict__ Qh, const unsigned short* __restrict__ Ql,
    const unsigned short* __restrict__ Kh, const unsigned short* __restrict__ Kl,
    const unsigned short* __restrict__ Vt, unsigned short* __restrict__ Ob){
  __shared__ unsigned short s_kh[4096], s_kl[4096], s_vt[4096];
  __shared__ unsigned short s_p[4096];
  int tid = threadIdx.x;
  int w = tid >> 6, l = tid & 63, lg = l >> 4, lr = l & 15;
  int gx = blockIdx.x;
  int qt = gx & 15, bh = gx >> 4;
  int b = bh >> 4, h = bh & 15;
  int q0 = qt * 64;
  int qs = q0 + w * 16;
  int rowb = b * 1024;

  // Q fragments (A-operand): row = lr, k-chunk = lg*8, two 32-wide d-steps
  short8 fqh[2], fql[2];
  for (int ds = 0; ds < 2; ds++){
    int off = (rowb + qs + lr) * 1024 + h * 64 + ds * 32 + lg * 8;
    fqh[ds] = *(const short8*)(Qh + off);
    fql[ds] = *(const short8*)(Ql + off);
  }

  floatx4 o_acc[4] = {};
  float m_r[4], l_r[4];
  for (int r = 0; r < 4; r++){ m_r[r] = -__builtin_inff(); l_r[r] = 0.f; }

  int ntile = qt + 1;
  for (int kt = 0; kt < ntile; kt++){
    int k0 = kt * 64;
    if (kt) __syncthreads();
    // stage K_hi/K_lo [64 keys][64 d] and Vt tile [64 d][64 keys], XOR-swizzled
    for (int rep = 0; rep < 2; rep++){
      int idx = rep * 256 + tid;        // 0..511
      int r = idx >> 3, c = idx & 7;
      int dst = r * 64 + ((((c * 16) ^ ((r & 7) << 4))) >> 1);
      int srcK = (rowb + k0 + r) * 1024 + h * 64 + c * 8;
      int srcV = (bh * 64 + r) * 1024 + k0 + c * 8;
      *(short8*)(s_kh + dst) = *(const short8*)(Kh + srcK);
      *(short8*)(s_kl + dst) = *(const short8*)(Kl + srcK);
      *(short8*)(s_vt + dst) = *(const short8*)(Vt + srcV);
    }
    __syncthreads();

    // QK^T: 4 key-subtiles x 2 d-steps x 3 split-MFMAs
    floatx4 sc[4] = {};
    for (int ds = 0; ds < 2; ds++)
      for (int s = 0; s < 4; s++){
        int r = s * 16 + lr;
        int off = r * 64 + ((((ds * 64 + lg * 16) ^ ((r & 7) << 4))) >> 1);
        short8 kh_f = *(const short8*)(s_kh + off);
        short8 kl_f = *(const short8*)(s_kl + off);
        sc[s] = __builtin_amdgcn_mfma_f32_16x16x32_bf16(fqh[ds], kh_f, sc[s], 0, 0, 0);
        sc[s] = __builtin_amdgcn_mfma_f32_16x16x32_bf16(fqh[ds], kl_f, sc[s], 0, 0, 0);
        sc[s] = __builtin_amdgcn_mfma_f32_16x16x32_bf16(fql[ds], kh_f, sc[s], 0, 0, 0);
      }

    for (int s = 0; s < 4; s++) sc[s] *= 0.125f;
    if (kt == ntile - 1){
      for (int s = 0; s < 4; s++)
        for (int r = 0; r < 4; r++)
          if (k0 + s * 16 + lr > qs + lg * 4 + r) sc[s][r] = -__builtin_inff();
    }

    // online softmax per q-row (row = lg*4 + r, cols spread over 16 lanes)
    float fac[4];
    for (int r = 0; r < 4; r++){
      float v = fmaxf(fmaxf(sc[0][r], sc[1][r]), fmaxf(sc[2][r], sc[3][r]));
      v = fmaxf(v, __shfl_xor(v, 1));
      v = fmaxf(v, __shfl_xor(v, 2));
      v = fmaxf(v, __shfl_xor(v, 4));
      v = fmaxf(v, __shfl_xor(v, 8));
      float mn = fmaxf(m_r[r], v);
      fac[r] = __expf(m_r[r] - mn);
      m_r[r] = mn;
      float ps = 0.f;
      for (int s = 0; s < 4; s++){
        float p = __expf(sc[s][r] - mn);
        sc[s][r] = p;
        ps += p;
      }
      ps += __shfl_xor(ps, 1); ps += __shfl_xor(ps, 2);
      ps += __shfl_xor(ps, 4); ps += __shfl_xor(ps, 8);
      l_r[r] = l_r[r] * fac[r] + ps;
      o_acc[0][r] *= fac[r]; o_acc[1][r] *= fac[r];
      o_acc[2][r] *= fac[r]; o_acc[3][r] *= fac[r];
    }

    // P -> LDS (bf16), per-wave region, same XOR swizzle
    for (int s = 0; s < 4; s++)
      for (int r = 0; r < 4; r++){
        int q = lg * 4 + r;
        int byte = ((s * 32 + lr * 2) ^ ((q & 7) << 4));
        s_p[(w * 16 + q) * 64 + (byte >> 1)] = f2bf(sc[s][r]);
      }

    // PV: 2 key-steps x 4 d-subtiles
    for (int kk = 0; kk < 2; kk++){
      int rq = lr;
      int offp = (w * 16 + rq) * 64 + ((((kk * 64 + lg * 16) ^ ((rq & 7) << 4))) >> 1);
      short8 pa = *(const short8*)(s_p + offp);
      for (int dsb = 0; dsb < 4; dsb++){
        int rv = dsb * 16 + lr;
        int offv = rv * 64 + ((((kk * 64 + lg * 16) ^ ((rv & 7) << 4))) >> 1);
        short8 vb = *(const short8*)(s_vt + offv);
        o_acc[dsb] = __builtin_amdgcn_mfma_f32_16x16x32_bf16(pa, vb, o_acc[dsb], 0, 0, 0);
      }
    }
  }

  for (int r = 0; r < 4; r++){
    float inv = 1.f / l_r[r];
    for (int dsb = 0; dsb < 4; dsb++){
      float v = o_acc[dsb][r] * inv;
      int q = qs + lg * 4 + r;
      Ob[(rowb + q) * 1024 + h * 64 + dsb * 16 + lr] = f2bf(v);
    }
  }
}

// ---------------------------------------------------------------------------
extern "C" void kernel_launch(void* const* d_in, const int* in_sizes, int n_in,
                              void* d_out, int out_size, void* d_ws, size_t ws_size,
                              hipStream_t stream){
  const float* x  = (const float*)d_in[0];
  const float* Wq = (const float*)d_in[1];
  const float* Wk = (const float*)d_in[2];
  const float* Wv = (const float*)d_in[3];
  const float* Wo = (const float*)d_in[4];
  const float* fr = (const float*)d_in[5];
  const float* pr = (const float*)d_in[6];

  char* ws = (char*)d_ws;
  size_t off = 0;
  auto alloc = [&](size_t bytes) -> char* {
    char* p = ws + off;
    off += (bytes + 255) & ~(size_t)255;
    return p;
  };
  float* fw = (float*)alloc(1024 * sizeof(float));
  float* pw = (float*)alloc(256);
  const size_t WB = (size_t)1024 * 1024 * 2;   // 2 MB (1024x1024 bf16)
  unsigned short* wq_h = (unsigned short*)alloc(WB);
  unsigned short* wq_l = (unsigned short*)alloc(WB);
  unsigned short* wk_h = (unsigned short*)alloc(WB);
  unsigned short* wk_l = (unsigned short*)alloc(WB);
  unsigned short* wv_b = (unsigned short*)alloc(WB);
  unsigned short* wo_b = (unsigned short*)alloc(WB);
  const size_t XB = (size_t)4096 * 1024 * 2;   // 8 MB (4096x1024 bf16)
  unsigned short* x_h = (unsigned short*)alloc(XB);
  unsigned short* x_l = (unsigned short*)alloc(XB);
  unsigned short* q_h = (unsigned short*)alloc(XB);
  unsigned short* q_l = (unsigned short*)alloc(XB);
  unsigned short* k_h = (unsigned short*)alloc(XB);
  unsigned short* k_l = (unsigned short*)alloc(XB);
  unsigned short* v_b = (unsigned short*)alloc(XB);
  unsigned short* vt  = x_h;   // alias: x_h dead after V GEMM
  unsigned short* o_b = x_l;   // alias: x_l dead after K GEMM

  k_prep_fw<<<1, 1024, 0, stream>>>(fr, pr, fw, pw);
  k_prep_w<<<1024, 256, 0, stream>>>(Wq, Wk, Wv, Wo, fw, pw,
                                     wq_h, wq_l, wk_h, wk_l, wv_b, wo_b);
  k_split_x<<<4096, 256, 0, stream>>>(x, x_h, x_l);

  dim3 gg(8, 32);
  k_gemm<1, 0><<<gg, 256, 0, stream>>>(x_h, x_l, wq_h, wq_l, (void*)q_h, q_l, 4096, 1024, 1024);
  k_gemm<1, 0><<<gg, 256, 0, stream>>>(x_h, x_l, wk_h, wk_l, (void*)k_h, k_l, 4096, 1024, 1024);
  k_gemm<0, 1><<<gg, 256, 0, stream>>>(x_h, nullptr, wv_b, nullptr, (void*)v_b, nullptr, 4096, 1024, 1024);
  k_transpose<<<1024, 256, 0, stream>>>(v_b, vt);
  k_attn<<<1024, 256, 0, stream>>>(q_h, q_l, k_h, k_l, vt, o_b);
  k_gemm<0, 2><<<gg, 256, 0, stream>>>(o_b, nullptr, wo_b, nullptr, d_out, nullptr, 4096, 1024, 1024);
}

// Round 2
// 261.580 us; speedup vs baseline: 1.0506x; 1.0506x over previous
//
#include <hip/hip_runtime.h>

typedef __attribute__((ext_vector_type(8))) short short8;
typedef __attribute__((ext_vector_type(4))) float float4v;
typedef __attribute__((ext_vector_type(4))) float floatx4;
typedef __attribute__((ext_vector_type(4))) unsigned short ushort4v;

#define DEV static __device__ __forceinline__

DEV unsigned short f2bf(float f){
  unsigned u = __builtin_bit_cast(unsigned, f);
  unsigned r = u + 0x7FFFu + ((u >> 16) & 1u);
  return (unsigned short)(r >> 16);
}
DEV float bf2f(unsigned short h){
  unsigned u = ((unsigned)h) << 16;
  return __builtin_bit_cast(float, u);
}
DEV float softplus_f(float x){
  if (x > 20.f) return x;
  return log1pf(expf(x));
}

DEV void gload16(const void* g, void* l){
  __builtin_amdgcn_global_load_lds(
      (const __attribute__((address_space(1))) unsigned int*)g,
      (__attribute__((address_space(3))) unsigned int*)l, 16, 0, 0);
}

// ---------------------------------------------------------------------------
// fw = reverse cumsum of softplus(freq_raw); pw = softplus(sym(pool_raw))
__global__ void k_prep_fw(const float* __restrict__ freq_raw,
                          const float* __restrict__ pool_raw,
                          float* __restrict__ fw, float* __restrict__ pw){
  __shared__ float s[1024];
  int d = threadIdx.x;
  s[d] = softplus_f(freq_raw[d]);
  __syncthreads();
  for (int off = 1; off < 1024; off <<= 1){
    float t = (d + off < 1024) ? s[d + off] : 0.f;
    __syncthreads();
    s[d] += t;
    __syncthreads();
  }
  fw[d] = s[d];
  if (d < 3) pw[d] = softplus_f((pool_raw[d] + pool_raw[2 - d]) * 0.5f);
}

// ---------------------------------------------------------------------------
// Build W~q = fw[n]*W_q (hi/lo bf16 split), W~k = conv3(W_k rows) (hi/lo),
// and plain bf16 W_v, W_o.
__global__ __launch_bounds__(256) void k_prep_w(
    const float* __restrict__ Wq, const float* __restrict__ Wk,
    const float* __restrict__ Wv, const float* __restrict__ Wo,
    const float* __restrict__ fw, const float* __restrict__ pw,
    unsigned short* __restrict__ wq_h, unsigned short* __restrict__ wq_l,
    unsigned short* __restrict__ wk_h, unsigned short* __restrict__ wk_l,
    unsigned short* __restrict__ wv_b, unsigned short* __restrict__ wo_b){
  int idx = blockIdx.x * 256 + threadIdx.x;      // 0..262143
  int n  = idx >> 8;
  int k4 = (idx & 255) << 2;
  float p0 = pw[0], p1 = pw[1], p2 = pw[2];
  float f = fw[n];
  int o = n * 1024 + k4;
  float4v q4 = *(const float4v*)(Wq + o);
  float4v k0v = *(const float4v*)(Wk + o);
  float4v km = {0.f,0.f,0.f,0.f}, kp = {0.f,0.f,0.f,0.f};
  if (n > 0)    km = *(const float4v*)(Wk + o - 1024);
  if (n < 1023) kp = *(const float4v*)(Wk + o + 1024);
  float4v v4 = *(const float4v*)(Wv + o);
  float4v o4 = *(const float4v*)(Wo + o);
  ushort4v qh, ql, kh, kl, vb, ob;
  for (int j = 0; j < 4; j++){
    float wq_ = f * q4[j];
    unsigned short h = f2bf(wq_);
    qh[j] = h; ql[j] = f2bf(wq_ - bf2f(h));
    float wk_ = p0 * km[j] + p1 * k0v[j] + p2 * kp[j];
    h = f2bf(wk_);
    kh[j] = h; kl[j] = f2bf(wk_ - bf2f(h));
    vb[j] = f2bf(v4[j]);
    ob[j] = f2bf(o4[j]);
  }
  *(ushort4v*)(wq_h + o) = qh; *(ushort4v*)(wq_l + o) = ql;
  *(ushort4v*)(wk_h + o) = kh; *(ushort4v*)(wk_l + o) = kl;
  *(ushort4v*)(wv_b + o) = vb; *(ushort4v*)(wo_b + o) = ob;
}

// ---------------------------------------------------------------------------
// Split x (fp32) into bf16 hi/lo
__global__ __launch_bounds__(256) void k_split_x(const float* __restrict__ x,
                                                 unsigned short* __restrict__ xh,
                                                 unsigned short* __restrict__ xl){
  int idx = blockIdx.x * 256 + threadIdx.x;
  int o = idx * 4;
  float4v v = *(const float4v*)(x + o);
  ushort4v h4, l4;
  for (int j = 0; j < 4; j++){
    unsigned short h = f2bf(v[j]);
    h4[j] = h; l4[j] = f2bf(v[j] - bf2f(h));
  }
  *(ushort4v*)(xh + o) = h4;
  *(ushort4v*)(xl + o) = l4;
}

// ---------------------------------------------------------------------------
// GEMM: C[M,N] = A[M,K] @ B[N,K]^T. BM=64 x BN=128 tile, BK=32, 4 waves (2x2),
// wave tile 32x64 (acc[2][4]). Staging via global_load_lds (linear LDS dest,
// source pre-swizzled with the same XOR the reads use).
// SPLIT: A,B given as hi+lo bf16, 3 MFMAs per fragment (drop lo*lo).
// OUT: 0 = write bf16 hi/lo pair, 1 = write bf16, 2 = write fp32.
template<int SPLIT, int OUT>
__global__ __launch_bounds__(256) void k_gemm(
    const unsigned short* __restrict__ Ah, const unsigned short* __restrict__ Al,
    const unsigned short* __restrict__ Bh, const unsigned short* __restrict__ Bl,
    void* __restrict__ out0, unsigned short* __restrict__ out1,
    int M, int N, int K){
  // A tile 64x32 = 2048 ush (4KB); B tile 128x32 = 4096 ush (8KB)
  __shared__ unsigned short lds[SPLIT ? 12288 : 6144];
  unsigned short* sAh = lds;
  unsigned short* sAl = lds + 2048;                     // split only
  unsigned short* sBh = lds + (SPLIT ? 4096 : 2048);
  unsigned short* sBl = lds + 8192;                     // split only

  int tid = threadIdx.x;
  int w = tid >> 6, l = tid & 63, lg = l >> 4, lr = l & 15;
  int wr = w >> 1, wc = w & 1;
  int n0 = blockIdx.x * 128, m0 = blockIdx.y * 64;

  floatx4 acc[2][4] = {};

  for (int kt = 0; kt < K; kt += 32){
    __syncthreads();
    // ---- stage A (256 chunks of 16B, one per thread) ----
    {
      int r = tid >> 2, c = tid & 3;
      int src = (m0 + r) * K + kt + (c ^ (r & 3)) * 8;
      gload16(Ah + src, sAh + w * 512);
      if constexpr (SPLIT) gload16(Al + src, sAl + w * 512);
    }
    // ---- stage B (512 chunks, two per thread) ----
    for (int rep = 0; rep < 2; rep++){
      int idx = rep * 256 + tid;
      int r = idx >> 2, c = idx & 3;
      int src = (n0 + r) * K + kt + (c ^ (r & 3)) * 8;
      gload16(Bh + src, sBh + rep * 2048 + w * 512);
      if constexpr (SPLIT) gload16(Bl + src, sBl + rep * 2048 + w * 512);
    }
    __syncthreads();

    short8 a_h[2], a_l[2], b_h[4], b_l[4];
    for (int ms = 0; ms < 2; ms++){
      int r = wr * 32 + ms * 16 + lr;
      int off = r * 32 + ((((lg * 16) ^ ((r & 3) << 4))) >> 1);
      a_h[ms] = *(const short8*)(sAh + off);
      if constexpr (SPLIT) a_l[ms] = *(const short8*)(sAl + off);
    }
    for (int ns = 0; ns < 4; ns++){
      int r = wc * 64 + ns * 16 + lr;
      int off = r * 32 + ((((lg * 16) ^ ((r & 3) << 4))) >> 1);
      b_h[ns] = *(const short8*)(sBh + off);
      if constexpr (SPLIT) b_l[ns] = *(const short8*)(sBl + off);
    }
    for (int ms = 0; ms < 2; ms++)
      for (int ns = 0; ns < 4; ns++){
        acc[ms][ns] = __builtin_amdgcn_mfma_f32_16x16x32_bf16(a_h[ms], b_h[ns], acc[ms][ns], 0, 0, 0);
        if constexpr (SPLIT){
          acc[ms][ns] = __builtin_amdgcn_mfma_f32_16x16x32_bf16(a_h[ms], b_l[ns], acc[ms][ns], 0, 0, 0);
          acc[ms][ns] = __builtin_amdgcn_mfma_f32_16x16x32_bf16(a_l[ms], b_h[ns], acc[ms][ns], 0, 0, 0);
        }
      }
  }
  for (int ms = 0; ms < 2; ms++)
    for (int ns = 0; ns < 4; ns++){
      int mrow = m0 + wr * 32 + ms * 16 + lg * 4;
      int ncol = n0 + wc * 64 + ns * 16 + lr;
      for (int rr = 0; rr < 4; rr++){
        float v = acc[ms][ns][rr];
        int o = (mrow + rr) * N + ncol;
        if constexpr (OUT == 0){
          unsigned short h = f2bf(v);
          ((unsigned short*)out0)[o] = h;
          out1[o] = f2bf(v - bf2f(h));
        } else if constexpr (OUT == 1){
          ((unsigned short*)out0)[o] = f2bf(v);
        } else {
          ((float*)out0)[o] = v;
        }
      }
    }
}

// ---------------------------------------------------------------------------
// Transpose V [B*S, H*hd] (bf16) -> Vt [B,H,hd,S]
__global__ __launch_bounds__(256) void k_transpose(const unsigned short* __restrict__ V,
                                                   unsigned short* __restrict__ Vt){
  __shared__ unsigned short t[64][72];
  int tid = threadIdx.x;
  int gx = blockIdx.x;
  int st = gx & 15, bh = gx >> 4;
  int b = bh >> 4, h = bh & 15;
  int s0 = st * 64;
  for (int idx = tid; idx < 512; idx += 256){
    int i = idx >> 3, c = idx & 7;
    short8 v = *(const short8*)(V + (b * 1024 + s0 + i) * 1024 + h * 64 + c * 8);
    *(short8*)(&t[i][c * 8]) = v;
  }
  __syncthreads();
  for (int idx = tid; idx < 512; idx += 256){
    int j = idx >> 3, ci = idx & 7;
    short8 o;
    for (int ii = 0; ii < 8; ii++) o[ii] = (short)t[ci * 8 + ii][j];
    *(short8*)(Vt + (bh * 64 + j) * 1024 + s0 + ci * 8) = o;
  }
}

// ---------------------------------------------------------------------------
// Flash attention, barrier-free. Grid: 1024 = qt-major (qt = gx>>6, bh = gx&63)
// so per-CU work is balanced and each bh's K/V stays XCD-local in L2.
// 4 waves x 16 q-rows; K/Kl/Vt fragments read directly from global (L1/L2);
// only the per-wave P tile goes through LDS.
__global__ __launch_bounds__(256) void k_attn(
    const unsigned short* __restrict__ Qh, const unsigned short* __restrict__ Ql,
    const unsigned short* __restrict__ Kh, const unsigned short* __restrict__ Kl,
    const unsigned short* __restrict__ Vt, unsigned short* __restrict__ Ob){
  __shared__ unsigned short s_p[4096];
  int tid = threadIdx.x;
  int w = tid >> 6, l = tid & 63, lg = l >> 4, lr = l & 15;
  int gx = blockIdx.x;
  int bh = gx & 63, qt = gx >> 6;
  int b = bh >> 4, h = bh & 15;
  int q0 = qt * 64;
  int qs = q0 + w * 16;
  int rowb = b * 1024;

  // Q fragments (A-operand): row = lr, k-chunk = lg*8, two 32-wide d-steps
  short8 fqh[2], fql[2];
  for (int ds = 0; ds < 2; ds++){
    int off = (rowb + qs + lr) * 1024 + h * 64 + ds * 32 + lg * 8;
    fqh[ds] = *(const short8*)(Qh + off);
    fql[ds] = *(const short8*)(Ql + off);
  }

  floatx4 o_acc[4] = {};
  float m_r[4], l_r[4];
  for (int r = 0; r < 4; r++){ m_r[r] = -__builtin_inff(); l_r[r] = 0.f; }

  int ntile = qt + 1;
  for (int kt = 0; kt < ntile; kt++){
    int k0 = kt * 64;

    // QK^T: 4 key-subtiles x 2 d-steps x 3 split-MFMAs, K read from global
    floatx4 sc[4] = {};
    for (int ds = 0; ds < 2; ds++)
      for (int s = 0; s < 4; s++){
        int off = (rowb + k0 + s * 16 + lr) * 1024 + h * 64 + ds * 32 + lg * 8;
        short8 kh_f = *(const short8*)(Kh + off);
        short8 kl_f = *(const short8*)(Kl + off);
        sc[s] = __builtin_amdgcn_mfma_f32_16x16x32_bf16(fqh[ds], kh_f, sc[s], 0, 0, 0);
        sc[s] = __builtin_amdgcn_mfma_f32_16x16x32_bf16(fqh[ds], kl_f, sc[s], 0, 0, 0);
        sc[s] = __builtin_amdgcn_mfma_f32_16x16x32_bf16(fql[ds], kh_f, sc[s], 0, 0, 0);
      }

    for (int s = 0; s < 4; s++) sc[s] *= 0.125f;
    if (kt == ntile - 1){
      for (int s = 0; s < 4; s++)
        for (int r = 0; r < 4; r++)
          if (k0 + s * 16 + lr > qs + lg * 4 + r) sc[s][r] = -__builtin_inff();
    }

    // online softmax per q-row (row = lg*4 + r, cols spread over 16 lanes)
    float fac[4];
    for (int r = 0; r < 4; r++){
      float v = fmaxf(fmaxf(sc[0][r], sc[1][r]), fmaxf(sc[2][r], sc[3][r]));
      v = fmaxf(v, __shfl_xor(v, 1));
      v = fmaxf(v, __shfl_xor(v, 2));
      v = fmaxf(v, __shfl_xor(v, 4));
      v = fmaxf(v, __shfl_xor(v, 8));
      float mn = fmaxf(m_r[r], v);
      fac[r] = __expf(m_r[r] - mn);
      m_r[r] = mn;
      float ps = 0.f;
      for (int s = 0; s < 4; s++){
        float p = __expf(sc[s][r] - mn);
        sc[s][r] = p;
        ps += p;
      }
      ps += __shfl_xor(ps, 1); ps += __shfl_xor(ps, 2);
      ps += __shfl_xor(ps, 4); ps += __shfl_xor(ps, 8);
      l_r[r] = l_r[r] * fac[r] + ps;
      o_acc[0][r] *= fac[r]; o_acc[1][r] *= fac[r];
      o_acc[2][r] *= fac[r]; o_acc[3][r] *= fac[r];
    }

    // P -> LDS (bf16), per-wave region, XOR swizzle (same-wave write/read only)
    for (int s = 0; s < 4; s++)
      for (int r = 0; r < 4; r++){
        int q = lg * 4 + r;
        int byte = ((s * 32 + lr * 2) ^ ((q & 7) << 4));
        s_p[(w * 16 + q) * 64 + (byte >> 1)] = f2bf(sc[s][r]);
      }

    // PV: 2 key-steps x 4 d-subtiles; Vt fragments read directly from global
    for (int kk = 0; kk < 2; kk++){
      int rq = lr;
      int offp = (w * 16 + rq) * 64 + ((((kk * 64 + lg * 16) ^ ((rq & 7) << 4))) >> 1);
      short8 pa = *(const short8*)(s_p + offp);
      for (int dsb = 0; dsb < 4; dsb++){
        int offv = (bh * 64 + dsb * 16 + lr) * 1024 + k0 + kk * 32 + lg * 8;
        short8 vb = *(const short8*)(Vt + offv);
        o_acc[dsb] = __builtin_amdgcn_mfma_f32_16x16x32_bf16(pa, vb, o_acc[dsb], 0, 0, 0);
      }
    }
  }

  for (int r = 0; r < 4; r++){
    float inv = 1.f / l_r[r];
    for (int dsb = 0; dsb < 4; dsb++){
      float v = o_acc[dsb][r] * inv;
      int q = qs + lg * 4 + r;
      Ob[(rowb + q) * 1024 + h * 64 + dsb * 16 + lr] = f2bf(v);
    }
  }
}

// ---------------------------------------------------------------------------
extern "C" void kernel_launch(void* const* d_in, const int* in_sizes, int n_in,
                              void* d_out, int out_size, void* d_ws, size_t ws_size,
                              hipStream_t stream){
  const float* x  = (const float*)d_in[0];
  const float* Wq = (const float*)d_in[1];
  const float* Wk = (const float*)d_in[2];
  const float* Wv = (const float*)d_in[3];
  const float* Wo = (const float*)d_in[4];
  const float* fr = (const float*)d_in[5];
  const float* pr = (const float*)d_in[6];

  char* ws = (char*)d_ws;
  size_t off = 0;
  auto alloc = [&](size_t bytes) -> char* {
    char* p = ws + off;
    off += (bytes + 255) & ~(size_t)255;
    return p;
  };
  float* fw = (float*)alloc(1024 * sizeof(float));
  float* pw = (float*)alloc(256);
  const size_t WB = (size_t)1024 * 1024 * 2;   // 2 MB (1024x1024 bf16)
  unsigned short* wq_h = (unsigned short*)alloc(WB);
  unsigned short* wq_l = (unsigned short*)alloc(WB);
  unsigned short* wk_h = (unsigned short*)alloc(WB);
  unsigned short* wk_l = (unsigned short*)alloc(WB);
  unsigned short* wv_b = (unsigned short*)alloc(WB);
  unsigned short* wo_b = (unsigned short*)alloc(WB);
  const size_t XB = (size_t)4096 * 1024 * 2;   // 8 MB (4096x1024 bf16)
  unsigned short* x_h = (unsigned short*)alloc(XB);
  unsigned short* x_l = (unsigned short*)alloc(XB);
  unsigned short* q_h = (unsigned short*)alloc(XB);
  unsigned short* q_l = (unsigned short*)alloc(XB);
  unsigned short* k_h = (unsigned short*)alloc(XB);
  unsigned short* k_l = (unsigned short*)alloc(XB);
  unsigned short* v_b = (unsigned short*)alloc(XB);
  unsigned short* vt  = x_h;   // alias: x_h dead after V GEMM
  unsigned short* o_b = x_l;   // alias: x_l dead after K GEMM

  k_prep_fw<<<1, 1024, 0, stream>>>(fr, pr, fw, pw);
  k_prep_w<<<1024, 256, 0, stream>>>(Wq, Wk, Wv, Wo, fw, pw,
                                     wq_h, wq_l, wk_h, wk_l, wv_b, wo_b);
  k_split_x<<<4096, 256, 0, stream>>>(x, x_h, x_l);

  dim3 gg(8, 64);   // N/128, M/64
  k_gemm<1, 0><<<gg, 256, 0, stream>>>(x_h, x_l, wq_h, wq_l, (void*)q_h, q_l, 4096, 1024, 1024);
  k_gemm<1, 0><<<gg, 256, 0, stream>>>(x_h, x_l, wk_h, wk_l, (void*)k_h, k_l, 4096, 1024, 1024);
  k_gemm<0, 1><<<gg, 256, 0, stream>>>(x_h, nullptr, wv_b, nullptr, (void*)v_b, nullptr, 4096, 1024, 1024);
  k_transpose<<<1024, 256, 0, stream>>>(v_b, vt);
  k_attn<<<1024, 256, 0, stream>>>(q_h, q_l, k_h, k_l, vt, o_b);
  k_gemm<0, 2><<<gg, 256, 0, stream>>>(o_b, nullptr, wo_b, nullptr, d_out, nullptr, 4096, 1024, 1024);
}

// Round 3
// 195.964 us; speedup vs baseline: 1.4024x; 1.3348x over previous
//
#include <hip/hip_runtime.h>

typedef __attribute__((ext_vector_type(8))) short short8;
typedef __attribute__((ext_vector_type(4))) float float4v;
typedef __attribute__((ext_vector_type(4))) float floatx4;
typedef __attribute__((ext_vector_type(4))) unsigned short ushort4v;

#define DEV static __device__ __forceinline__

DEV unsigned short f2bf(float f){
  unsigned u = __builtin_bit_cast(unsigned, f);
  unsigned r = u + 0x7FFFu + ((u >> 16) & 1u);
  return (unsigned short)(r >> 16);
}
DEV float bf2f(unsigned short h){
  unsigned u = ((unsigned)h) << 16;
  return __builtin_bit_cast(float, u);
}
DEV float softplus_f(float x){
  if (x > 20.f) return x;
  return log1pf(expf(x));
}

DEV void gload16(const void* g, void* l){
  __builtin_amdgcn_global_load_lds(
      (const __attribute__((address_space(1))) unsigned int*)g,
      (__attribute__((address_space(3))) unsigned int*)l, 16, 0, 0);
}

// ---------------------------------------------------------------------------
// fw = reverse cumsum of softplus(freq_raw); pw = softplus(sym(pool_raw))
__global__ void k_prep_fw(const float* __restrict__ freq_raw,
                          const float* __restrict__ pool_raw,
                          float* __restrict__ fw, float* __restrict__ pw){
  __shared__ float s[1024];
  int d = threadIdx.x;
  s[d] = softplus_f(freq_raw[d]);
  __syncthreads();
  for (int off = 1; off < 1024; off <<= 1){
    float t = (d + off < 1024) ? s[d + off] : 0.f;
    __syncthreads();
    s[d] += t;
    __syncthreads();
  }
  fw[d] = s[d];
  if (d < 3) pw[d] = softplus_f((pool_raw[d] + pool_raw[2 - d]) * 0.5f);
}

// ---------------------------------------------------------------------------
// Build W~q = (fw[n]/8)*W_q (hi/lo bf16 split) -- 1/sqrt(hd) folded in here,
// W~k = conv3(W_k rows) (hi/lo), and plain bf16 W_v, W_o.
__global__ __launch_bounds__(256) void k_prep_w(
    const float* __restrict__ Wq, const float* __restrict__ Wk,
    const float* __restrict__ Wv, const float* __restrict__ Wo,
    const float* __restrict__ fw, const float* __restrict__ pw,
    unsigned short* __restrict__ wq_h, unsigned short* __restrict__ wq_l,
    unsigned short* __restrict__ wk_h, unsigned short* __restrict__ wk_l,
    unsigned short* __restrict__ wv_b, unsigned short* __restrict__ wo_b){
  int idx = blockIdx.x * 256 + threadIdx.x;      // 0..262143
  int n  = idx >> 8;
  int k4 = (idx & 255) << 2;
  float p0 = pw[0], p1 = pw[1], p2 = pw[2];
  float f = fw[n] * 0.125f;
  int o = n * 1024 + k4;
  float4v q4 = *(const float4v*)(Wq + o);
  float4v k0v = *(const float4v*)(Wk + o);
  float4v km = {0.f,0.f,0.f,0.f}, kp = {0.f,0.f,0.f,0.f};
  if (n > 0)    km = *(const float4v*)(Wk + o - 1024);
  if (n < 1023) kp = *(const float4v*)(Wk + o + 1024);
  float4v v4 = *(const float4v*)(Wv + o);
  float4v o4 = *(const float4v*)(Wo + o);
  ushort4v qh, ql, kh, kl, vb, ob;
  for (int j = 0; j < 4; j++){
    float wq_ = f * q4[j];
    unsigned short h = f2bf(wq_);
    qh[j] = h; ql[j] = f2bf(wq_ - bf2f(h));
    float wk_ = p0 * km[j] + p1 * k0v[j] + p2 * kp[j];
    h = f2bf(wk_);
    kh[j] = h; kl[j] = f2bf(wk_ - bf2f(h));
    vb[j] = f2bf(v4[j]);
    ob[j] = f2bf(o4[j]);
  }
  *(ushort4v*)(wq_h + o) = qh; *(ushort4v*)(wq_l + o) = ql;
  *(ushort4v*)(wk_h + o) = kh; *(ushort4v*)(wk_l + o) = kl;
  *(ushort4v*)(wv_b + o) = vb; *(ushort4v*)(wo_b + o) = ob;
}

// ---------------------------------------------------------------------------
// Split x (fp32) into bf16 hi/lo
__global__ __launch_bounds__(256) void k_split_x(const float* __restrict__ x,
                                                 unsigned short* __restrict__ xh,
                                                 unsigned short* __restrict__ xl){
  int idx = blockIdx.x * 256 + threadIdx.x;
  int o = idx * 4;
  float4v v = *(const float4v*)(x + o);
  ushort4v h4, l4;
  for (int j = 0; j < 4; j++){
    unsigned short h = f2bf(v[j]);
    h4[j] = h; l4[j] = f2bf(v[j] - bf2f(h));
  }
  *(ushort4v*)(xh + o) = h4;
  *(ushort4v*)(xl + o) = l4;
}

// ---------------------------------------------------------------------------
// GEMM: C[M,N] = A[M,K] @ B[N,K]^T. BM=64 x BN=128 tile, BK=32, 4 waves (2x2),
// wave tile 32x64. Double-buffered LDS, 2-phase pipeline: STAGE(t+1) issued
// before compute(t), one __syncthreads per K-step drains vmcnt.
// SPLIT: A,B given as hi+lo bf16, 3 MFMAs per fragment (drop lo*lo).
// OUT: 0 = write bf16 hi/lo pair, 1 = write bf16, 2 = write fp32.
template<int SPLIT, int OUT>
__global__ __launch_bounds__(256) void k_gemm(
    const unsigned short* __restrict__ Ah, const unsigned short* __restrict__ Al,
    const unsigned short* __restrict__ Bh, const unsigned short* __restrict__ Bl,
    void* __restrict__ out0, unsigned short* __restrict__ out1,
    int M, int N, int K){
  constexpr int BUFN = SPLIT ? 12288 : 6144;   // ush per buffer
  __shared__ unsigned short lds[2 * BUFN];

  int tid = threadIdx.x;
  int w = tid >> 6, l = tid & 63, lg = l >> 4, lr = l & 15;
  int wr = w >> 1, wc = w & 1;
  int n0 = blockIdx.x * 128, m0 = blockIdx.y * 64;

  auto stage = [&](int kt, int bufi){
    unsigned short* buf = lds + bufi * BUFN;
    unsigned short* bAh = buf;
    unsigned short* bAl = buf + 2048;
    unsigned short* bBh = buf + (SPLIT ? 4096 : 2048);
    unsigned short* bBl = buf + 8192;
    {
      int r = tid >> 2, c = tid & 3;
      int src = (m0 + r) * K + kt + (c ^ (r & 3)) * 8;
      gload16(Ah + src, bAh + w * 512);
      if constexpr (SPLIT) gload16(Al + src, bAl + w * 512);
    }
    for (int rep = 0; rep < 2; rep++){
      int idx = rep * 256 + tid;
      int r = idx >> 2, c = idx & 3;
      int src = (n0 + r) * K + kt + (c ^ (r & 3)) * 8;
      gload16(Bh + src, bBh + rep * 2048 + w * 512);
      if constexpr (SPLIT) gload16(Bl + src, bBl + rep * 2048 + w * 512);
    }
  };

  floatx4 acc[2][4] = {};

  stage(0, 0);
  __syncthreads();
  int cur = 0;
  for (int kt = 0; kt < K; kt += 32){
    if (kt + 32 < K) stage(kt + 32, cur ^ 1);

    const unsigned short* buf = lds + cur * BUFN;
    const unsigned short* sAh = buf;
    const unsigned short* sAl = buf + 2048;
    const unsigned short* sBh = buf + (SPLIT ? 4096 : 2048);
    const unsigned short* sBl = buf + 8192;

    short8 a_h[2], a_l[2], b_h[4], b_l[4];
    for (int ms = 0; ms < 2; ms++){
      int r = wr * 32 + ms * 16 + lr;
      int off = r * 32 + ((((lg * 16) ^ ((r & 3) << 4))) >> 1);
      a_h[ms] = *(const short8*)(sAh + off);
      if constexpr (SPLIT) a_l[ms] = *(const short8*)(sAl + off);
    }
    for (int ns = 0; ns < 4; ns++){
      int r = wc * 64 + ns * 16 + lr;
      int off = r * 32 + ((((lg * 16) ^ ((r & 3) << 4))) >> 1);
      b_h[ns] = *(const short8*)(sBh + off);
      if constexpr (SPLIT) b_l[ns] = *(const short8*)(sBl + off);
    }
    for (int ms = 0; ms < 2; ms++)
      for (int ns = 0; ns < 4; ns++){
        acc[ms][ns] = __builtin_amdgcn_mfma_f32_16x16x32_bf16(a_h[ms], b_h[ns], acc[ms][ns], 0, 0, 0);
        if constexpr (SPLIT){
          acc[ms][ns] = __builtin_amdgcn_mfma_f32_16x16x32_bf16(a_h[ms], b_l[ns], acc[ms][ns], 0, 0, 0);
          acc[ms][ns] = __builtin_amdgcn_mfma_f32_16x16x32_bf16(a_l[ms], b_h[ns], acc[ms][ns], 0, 0, 0);
        }
      }
    __syncthreads();
    cur ^= 1;
  }

  for (int ms = 0; ms < 2; ms++)
    for (int ns = 0; ns < 4; ns++){
      int mrow = m0 + wr * 32 + ms * 16 + lg * 4;
      int ncol = n0 + wc * 64 + ns * 16 + lr;
      for (int rr = 0; rr < 4; rr++){
        float v = acc[ms][ns][rr];
        int o = (mrow + rr) * N + ncol;
        if constexpr (OUT == 0){
          unsigned short h = f2bf(v);
          ((unsigned short*)out0)[o] = h;
          out1[o] = f2bf(v - bf2f(h));
        } else if constexpr (OUT == 1){
          ((unsigned short*)out0)[o] = f2bf(v);
        } else {
          ((float*)out0)[o] = v;
        }
      }
    }
}

// ---------------------------------------------------------------------------
// Transpose V [B*S, H*hd] (bf16) -> Vt [B,H,hd,S]
__global__ __launch_bounds__(256) void k_transpose(const unsigned short* __restrict__ V,
                                                   unsigned short* __restrict__ Vt){
  __shared__ unsigned short t[64][72];
  int tid = threadIdx.x;
  int gx = blockIdx.x;
  int st = gx & 15, bh = gx >> 4;
  int b = bh >> 4, h = bh & 15;
  int s0 = st * 64;
  for (int idx = tid; idx < 512; idx += 256){
    int i = idx >> 3, c = idx & 7;
    short8 v = *(const short8*)(V + (b * 1024 + s0 + i) * 1024 + h * 64 + c * 8);
    *(short8*)(&t[i][c * 8]) = v;
  }
  __syncthreads();
  for (int idx = tid; idx < 512; idx += 256){
    int j = idx >> 3, ci = idx & 7;
    short8 o;
    for (int ii = 0; ii < 8; ii++) o[ii] = (short)t[ci * 8 + ii][j];
    *(short8*)(Vt + (bh * 64 + j) * 1024 + s0 + ci * 8) = o;
  }
}

// ---------------------------------------------------------------------------
// Flash attention. Grid qt-major (qt = gx>>6, bh = gx&63) for balance + L2
// locality. 4 waves x 16 q-rows. K_hi/K_lo/V staged in double-buffered LDS
// via global_load_lds (linear dest, pre-swizzled source); 2-phase pipeline,
// one __syncthreads per k-tile. QK^T split-3x bf16, PV plain bf16.
// fw already carries the 1/sqrt(hd) scale.
__global__ __launch_bounds__(256) void k_attn(
    const unsigned short* __restrict__ Qh, const unsigned short* __restrict__ Ql,
    const unsigned short* __restrict__ Kh, const unsigned short* __restrict__ Kl,
    const unsigned short* __restrict__ Vt, unsigned short* __restrict__ Ob){
  __shared__ unsigned short s_k[2][12288];   // per buf: Kh 4096 | Kl 4096 | V 4096
  __shared__ unsigned short s_p[4096];
  int tid = threadIdx.x;
  int w = tid >> 6, l = tid & 63, lg = l >> 4, lr = l & 15;
  int gx = blockIdx.x;
  int bh = gx & 63, qt = gx >> 6;
  int b = bh >> 4, h = bh & 15;
  int q0 = qt * 64;
  int qs = q0 + w * 16;
  int rowb = b * 1024;

  auto stage = [&](int kt, int bufi){
    int k0 = kt * 64;
    unsigned short* buf = s_k[bufi];
    for (int rep = 0; rep < 2; rep++){
      int idx = rep * 256 + tid;
      int r = idx >> 3, c = idx & 7;
      int cs = c ^ (r & 7);                        // pre-swizzled source chunk
      int srcK = (rowb + k0 + r) * 1024 + h * 64 + cs * 8;
      int srcV = (bh * 64 + r) * 1024 + k0 + cs * 8;
      unsigned short* dst = buf + rep * 2048 + w * 512;   // + lane*16B by HW
      gload16(Kh + srcK, dst);
      gload16(Kl + srcK, dst + 4096);
      gload16(Vt + srcV, dst + 8192);
    }
  };

  // Q fragments (A-operand): row = lr, k-chunk = lg*8, two 32-wide d-steps
  short8 fqh[2], fql[2];
  for (int ds = 0; ds < 2; ds++){
    int off = (rowb + qs + lr) * 1024 + h * 64 + ds * 32 + lg * 8;
    fqh[ds] = *(const short8*)(Qh + off);
    fql[ds] = *(const short8*)(Ql + off);
  }

  floatx4 o_acc[4] = {};
  float m_r[4], l_r[4];
  for (int r = 0; r < 4; r++){ m_r[r] = -__builtin_inff(); l_r[r] = 0.f; }

  int ntile = qt + 1;
  stage(0, 0);
  __syncthreads();
  int cur = 0;
  for (int kt = 0; kt < ntile; kt++){
    int k0 = kt * 64;
    if (kt + 1 < ntile) stage(kt + 1, cur ^ 1);
    const unsigned short* kb = s_k[cur];

    // QK^T: 4 key-subtiles x 2 d-steps x 3 split-MFMAs
    floatx4 sc[4] = {};
    for (int ds = 0; ds < 2; ds++)
      for (int s = 0; s < 4; s++){
        int r = s * 16 + lr;
        int off = r * 64 + (((ds * 4 + lg) ^ (r & 7)) * 8);
        short8 kh_f = *(const short8*)(kb + off);
        short8 kl_f = *(const short8*)(kb + 4096 + off);
        sc[s] = __builtin_amdgcn_mfma_f32_16x16x32_bf16(fqh[ds], kh_f, sc[s], 0, 0, 0);
        sc[s] = __builtin_amdgcn_mfma_f32_16x16x32_bf16(fqh[ds], kl_f, sc[s], 0, 0, 0);
        sc[s] = __builtin_amdgcn_mfma_f32_16x16x32_bf16(fql[ds], kh_f, sc[s], 0, 0, 0);
      }

    if (kt == ntile - 1){
      for (int s = 0; s < 4; s++)
        for (int r = 0; r < 4; r++)
          if (k0 + s * 16 + lr > qs + lg * 4 + r) sc[s][r] = -__builtin_inff();
    }

    // online softmax per q-row (row = lg*4 + r, cols spread over 16 lanes)
    float fac[4];
    for (int r = 0; r < 4; r++){
      float v = fmaxf(fmaxf(sc[0][r], sc[1][r]), fmaxf(sc[2][r], sc[3][r]));
      v = fmaxf(v, __shfl_xor(v, 1));
      v = fmaxf(v, __shfl_xor(v, 2));
      v = fmaxf(v, __shfl_xor(v, 4));
      v = fmaxf(v, __shfl_xor(v, 8));
      float mn = fmaxf(m_r[r], v);
      fac[r] = __expf(m_r[r] - mn);
      m_r[r] = mn;
      float ps = 0.f;
      for (int s = 0; s < 4; s++){
        float p = __expf(sc[s][r] - mn);
        sc[s][r] = p;
        ps += p;
      }
      ps += __shfl_xor(ps, 1); ps += __shfl_xor(ps, 2);
      ps += __shfl_xor(ps, 4); ps += __shfl_xor(ps, 8);
      l_r[r] = l_r[r] * fac[r] + ps;
      o_acc[0][r] *= fac[r]; o_acc[1][r] *= fac[r];
      o_acc[2][r] *= fac[r]; o_acc[3][r] *= fac[r];
    }

    // P -> LDS (bf16), per-wave region, XOR swizzle (same-wave write/read only)
    for (int s = 0; s < 4; s++)
      for (int r = 0; r < 4; r++){
        int q = lg * 4 + r;
        int byte = ((s * 32 + lr * 2) ^ ((q & 7) << 4));
        s_p[(w * 16 + q) * 64 + (byte >> 1)] = f2bf(sc[s][r]);
      }

    // PV: 2 key-steps x 4 d-subtiles, V from LDS
    for (int kk = 0; kk < 2; kk++){
      int rq = lr;
      int offp = (w * 16 + rq) * 64 + ((((kk * 64 + lg * 16) ^ ((rq & 7) << 4))) >> 1);
      short8 pa = *(const short8*)(s_p + offp);
      for (int dsb = 0; dsb < 4; dsb++){
        int rv = dsb * 16 + lr;
        int offv = rv * 64 + (((kk * 4 + lg) ^ (rv & 7)) * 8);
        short8 vb = *(const short8*)(kb + 8192 + offv);
        o_acc[dsb] = __builtin_amdgcn_mfma_f32_16x16x32_bf16(pa, vb, o_acc[dsb], 0, 0, 0);
      }
    }
    __syncthreads();
    cur ^= 1;
  }

  for (int r = 0; r < 4; r++){
    float inv = 1.f / l_r[r];
    for (int dsb = 0; dsb < 4; dsb++){
      float v = o_acc[dsb][r] * inv;
      int q = qs + lg * 4 + r;
      Ob[(rowb + q) * 1024 + h * 64 + dsb * 16 + lr] = f2bf(v);
    }
  }
}

// ---------------------------------------------------------------------------
extern "C" void kernel_launch(void* const* d_in, const int* in_sizes, int n_in,
                              void* d_out, int out_size, void* d_ws, size_t ws_size,
                              hipStream_t stream){
  const float* x  = (const float*)d_in[0];
  const float* Wq = (const float*)d_in[1];
  const float* Wk = (const float*)d_in[2];
  const float* Wv = (const float*)d_in[3];
  const float* Wo = (const float*)d_in[4];
  const float* fr = (const float*)d_in[5];
  const float* pr = (const float*)d_in[6];

  char* ws = (char*)d_ws;
  size_t off = 0;
  auto alloc = [&](size_t bytes) -> char* {
    char* p = ws + off;
    off += (bytes + 255) & ~(size_t)255;
    return p;
  };
  float* fw = (float*)alloc(1024 * sizeof(float));
  float* pw = (float*)alloc(256);
  const size_t WB = (size_t)1024 * 1024 * 2;   // 2 MB (1024x1024 bf16)
  unsigned short* wq_h = (unsigned short*)alloc(WB);
  unsigned short* wq_l = (unsigned short*)alloc(WB);
  unsigned short* wk_h = (unsigned short*)alloc(WB);
  unsigned short* wk_l = (unsigned short*)alloc(WB);
  unsigned short* wv_b = (unsigned short*)alloc(WB);
  unsigned short* wo_b = (unsigned short*)alloc(WB);
  const size_t XB = (size_t)4096 * 1024 * 2;   // 8 MB (4096x1024 bf16)
  unsigned short* x_h = (unsigned short*)alloc(XB);
  unsigned short* x_l = (unsigned short*)alloc(XB);
  unsigned short* q_h = (unsigned short*)alloc(XB);
  unsigned short* q_l = (unsigned short*)alloc(XB);
  unsigned short* k_h = (unsigned short*)alloc(XB);
  unsigned short* k_l = (unsigned short*)alloc(XB);
  unsigned short* v_b = (unsigned short*)alloc(XB);
  unsigned short* vt  = x_h;   // alias: x_h dead after V GEMM
  unsigned short* o_b = x_l;   // alias: x_l dead after K GEMM

  k_prep_fw<<<1, 1024, 0, stream>>>(fr, pr, fw, pw);
  k_prep_w<<<1024, 256, 0, stream>>>(Wq, Wk, Wv, Wo, fw, pw,
                                     wq_h, wq_l, wk_h, wk_l, wv_b, wo_b);
  k_split_x<<<4096, 256, 0, stream>>>(x, x_h, x_l);

  dim3 gg(8, 64);   // N/128, M/64
  k_gemm<1, 0><<<gg, 256, 0, stream>>>(x_h, x_l, wq_h, wq_l, (void*)q_h, q_l, 4096, 1024, 1024);
  k_gemm<1, 0><<<gg, 256, 0, stream>>>(x_h, x_l, wk_h, wk_l, (void*)k_h, k_l, 4096, 1024, 1024);
  k_gemm<0, 1><<<gg, 256, 0, stream>>>(x_h, nullptr, wv_b, nullptr, (void*)v_b, nullptr, 4096, 1024, 1024);
  k_transpose<<<1024, 256, 0, stream>>>(v_b, vt);
  k_attn<<<1024, 256, 0, stream>>>(q_h, q_l, k_h, k_l, vt, o_b);
  k_gemm<0, 2><<<gg, 256, 0, stream>>>(o_b, nullptr, wo_b, nullptr, d_out, nullptr, 4096, 1024, 1024);
}

// Round 5
// 189.492 us; speedup vs baseline: 1.4502x; 1.0342x over previous
//
#include <hip/hip_runtime.h>

typedef __attribute__((ext_vector_type(8))) short short8;
typedef __attribute__((ext_vector_type(4))) float float4v;
typedef __attribute__((ext_vector_type(4))) float floatx4;
typedef __attribute__((ext_vector_type(4))) unsigned short ushort4v;

#define DEV static __device__ __forceinline__
#define MFMA __builtin_amdgcn_mfma_f32_16x16x32_bf16

DEV unsigned short f2bf(float f){
  unsigned u = __builtin_bit_cast(unsigned, f);
  unsigned r = u + 0x7FFFu + ((u >> 16) & 1u);
  return (unsigned short)(r >> 16);
}
DEV float bf2f(unsigned short h){
  unsigned u = ((unsigned)h) << 16;
  return __builtin_bit_cast(float, u);
}
DEV float softplus_f(float x){
  if (x > 20.f) return x;
  return log1pf(expf(x));
}

DEV void gload16(const void* g, void* l){
  __builtin_amdgcn_global_load_lds(
      (const __attribute__((address_space(1))) unsigned int*)g,
      (__attribute__((address_space(3))) unsigned int*)l, 16, 0, 0);
}

// ---------------------------------------------------------------------------
__global__ void k_prep_fw(const float* __restrict__ freq_raw,
                          const float* __restrict__ pool_raw,
                          float* __restrict__ fw, float* __restrict__ pw){
  __shared__ float s[1024];
  int d = threadIdx.x;
  s[d] = softplus_f(freq_raw[d]);
  __syncthreads();
  for (int off = 1; off < 1024; off <<= 1){
    float t = (d + off < 1024) ? s[d + off] : 0.f;
    __syncthreads();
    s[d] += t;
    __syncthreads();
  }
  fw[d] = s[d];
  if (d < 3) pw[d] = softplus_f((pool_raw[d] + pool_raw[2 - d]) * 0.5f);
}

// ---------------------------------------------------------------------------
// W~q = (fw/8)*W_q hi/lo; W~k = conv3(W_k) hi/lo; plain bf16 W_v, W_o.
__global__ __launch_bounds__(256) void k_prep_w(
    const float* __restrict__ Wq, const float* __restrict__ Wk,
    const float* __restrict__ Wv, const float* __restrict__ Wo,
    const float* __restrict__ fw, const float* __restrict__ pw,
    unsigned short* __restrict__ wq_h, unsigned short* __restrict__ wq_l,
    unsigned short* __restrict__ wk_h, unsigned short* __restrict__ wk_l,
    unsigned short* __restrict__ wv_b, unsigned short* __restrict__ wo_b){
  int idx = blockIdx.x * 256 + threadIdx.x;
  int n  = idx >> 8;
  int k4 = (idx & 255) << 2;
  float p0 = pw[0], p1 = pw[1], p2 = pw[2];
  float f = fw[n] * 0.125f;
  int o = n * 1024 + k4;
  float4v q4 = *(const float4v*)(Wq + o);
  float4v k0v = *(const float4v*)(Wk + o);
  float4v km = {0.f,0.f,0.f,0.f}, kp = {0.f,0.f,0.f,0.f};
  if (n > 0)    km = *(const float4v*)(Wk + o - 1024);
  if (n < 1023) kp = *(const float4v*)(Wk + o + 1024);
  float4v v4 = *(const float4v*)(Wv + o);
  float4v o4 = *(const float4v*)(Wo + o);
  ushort4v qh, ql, kh, kl, vb, ob;
  for (int j = 0; j < 4; j++){
    float wq_ = f * q4[j];
    unsigned short h = f2bf(wq_);
    qh[j] = h; ql[j] = f2bf(wq_ - bf2f(h));
    float wk_ = p0 * km[j] + p1 * k0v[j] + p2 * kp[j];
    h = f2bf(wk_);
    kh[j] = h; kl[j] = f2bf(wk_ - bf2f(h));
    vb[j] = f2bf(v4[j]);
    ob[j] = f2bf(o4[j]);
  }
  *(ushort4v*)(wq_h + o) = qh; *(ushort4v*)(wq_l + o) = ql;
  *(ushort4v*)(wk_h + o) = kh; *(ushort4v*)(wk_l + o) = kl;
  *(ushort4v*)(wv_b + o) = vb; *(ushort4v*)(wo_b + o) = ob;
}

// ---------------------------------------------------------------------------
__global__ __launch_bounds__(256) void k_split_x(const float* __restrict__ x,
                                                 unsigned short* __restrict__ xh,
                                                 unsigned short* __restrict__ xl){
  int idx = blockIdx.x * 256 + threadIdx.x;
  int o = idx * 4;
  float4v v = *(const float4v*)(x + o);
  ushort4v h4, l4;
  for (int j = 0; j < 4; j++){
    unsigned short h = f2bf(v[j]);
    h4[j] = h; l4[j] = f2bf(v[j] - bf2f(h));
  }
  *(ushort4v*)(xh + o) = h4;
  *(ushort4v*)(xl + o) = l4;
}

// ---------------------------------------------------------------------------
// Fused Q+K projection GEMM: Q = x@Wq^T, K = x@Wk^T, both split-3x hi/lo.
// BM=64, BN=64, BK=32, 4 waves (2x2, wave tile 32x32 per output matrix).
// Shares A (x hi/lo) staging across both outputs; double-buffered LDS.
__global__ __launch_bounds__(256) void k_gemm_qk(
    const unsigned short* __restrict__ Ah, const unsigned short* __restrict__ Al,
    const unsigned short* __restrict__ Bqh, const unsigned short* __restrict__ Bql,
    const unsigned short* __restrict__ Bkh, const unsigned short* __restrict__ Bkl,
    unsigned short* __restrict__ qh_o, unsigned short* __restrict__ ql_o,
    unsigned short* __restrict__ kh_o, unsigned short* __restrict__ kl_o){
  __shared__ unsigned short lds[2][12288];  // Ah|Al|Bqh|Bql|Bkh|Bkl x 2048 ush
  int tid = threadIdx.x;
  int w = tid >> 6, l = tid & 63, lg = l >> 4, lr = l & 15;
  int wr = w >> 1, wc = w & 1;
  int g = blockIdx.x;
  int mblk = (g & 7) * 8 + ((g >> 3) & 7);
  int nblk = g >> 6;
  int m0 = mblk * 64, n0 = nblk * 64;

  auto stage = [&](int kt, int bufi){
    unsigned short* buf = lds[bufi];
    int r = tid >> 2, c = tid & 3;
    int cs = (c ^ (r & 3)) * 8;
    int srcA = (m0 + r) * 1024 + kt + cs;
    int srcB = (n0 + r) * 1024 + kt + cs;
    unsigned short* dst = buf + w * 512;
    gload16(Ah + srcA, dst);
    gload16(Al + srcA, dst + 2048);
    gload16(Bqh + srcB, dst + 4096);
    gload16(Bql + srcB, dst + 6144);
    gload16(Bkh + srcB, dst + 8192);
    gload16(Bkl + srcB, dst + 10240);
  };

  floatx4 aq[2][2] = {}, ak[2][2] = {};
  stage(0, 0);
  __syncthreads();
  int cur = 0;
  for (int kt = 0; kt < 1024; kt += 32){
    if (kt + 32 < 1024) stage(kt + 32, cur ^ 1);
    const unsigned short* buf = lds[cur];
    short8 a_h[2], a_l[2], bq_h[2], bq_l[2], bk_h[2], bk_l[2];
    for (int ms = 0; ms < 2; ms++){
      int r = wr * 32 + ms * 16 + lr;
      int off = r * 32 + ((lg ^ (r & 3)) * 8);
      a_h[ms] = *(const short8*)(buf + off);
      a_l[ms] = *(const short8*)(buf + 2048 + off);
    }
    for (int ns = 0; ns < 2; ns++){
      int r = wc * 32 + ns * 16 + lr;
      int off = r * 32 + ((lg ^ (r & 3)) * 8);
      bq_h[ns] = *(const short8*)(buf + 4096 + off);
      bq_l[ns] = *(const short8*)(buf + 6144 + off);
      bk_h[ns] = *(const short8*)(buf + 8192 + off);
      bk_l[ns] = *(const short8*)(buf + 10240 + off);
    }
    for (int ms = 0; ms < 2; ms++)
      for (int ns = 0; ns < 2; ns++){
        aq[ms][ns] = MFMA(a_h[ms], bq_h[ns], aq[ms][ns], 0, 0, 0);
        aq[ms][ns] = MFMA(a_h[ms], bq_l[ns], aq[ms][ns], 0, 0, 0);
        aq[ms][ns] = MFMA(a_l[ms], bq_h[ns], aq[ms][ns], 0, 0, 0);
        ak[ms][ns] = MFMA(a_h[ms], bk_h[ns], ak[ms][ns], 0, 0, 0);
        ak[ms][ns] = MFMA(a_h[ms], bk_l[ns], ak[ms][ns], 0, 0, 0);
        ak[ms][ns] = MFMA(a_l[ms], bk_h[ns], ak[ms][ns], 0, 0, 0);
      }
    __syncthreads();
    cur ^= 1;
  }
  for (int ms = 0; ms < 2; ms++)
    for (int ns = 0; ns < 2; ns++){
      int mrow = m0 + wr * 32 + ms * 16 + lg * 4;
      int ncol = n0 + wc * 32 + ns * 16 + lr;
      for (int rr = 0; rr < 4; rr++){
        int o = (mrow + rr) * 1024 + ncol;
        float v = aq[ms][ns][rr];
        unsigned short hh = f2bf(v);
        qh_o[o] = hh; ql_o[o] = f2bf(v - bf2f(hh));
        v = ak[ms][ns][rr];
        hh = f2bf(v);
        kh_o[o] = hh; kl_o[o] = f2bf(v - bf2f(hh));
      }
    }
}

// ---------------------------------------------------------------------------
// Plain GEMM (V projection / output projection).
template<int OUT>
__global__ __launch_bounds__(256) void k_gemm(
    const unsigned short* __restrict__ Ah, const unsigned short* __restrict__ Bh,
    void* __restrict__ out0, int M, int N, int K){
  constexpr int BUFN = 6144;
  __shared__ unsigned short lds[2 * BUFN];
  int tid = threadIdx.x;
  int w = tid >> 6, l = tid & 63, lg = l >> 4, lr = l & 15;
  int wr = w >> 1, wc = w & 1;
  int n0 = blockIdx.x * 128, m0 = blockIdx.y * 64;

  auto stage = [&](int kt, int bufi){
    unsigned short* buf = lds + bufi * BUFN;
    { int r = tid >> 2, c = tid & 3;
      int src = (m0 + r) * K + kt + (c ^ (r & 3)) * 8;
      gload16(Ah + src, buf + w * 512); }
    for (int rep = 0; rep < 2; rep++){
      int idx = rep * 256 + tid;
      int r = idx >> 2, c = idx & 3;
      int src = (n0 + r) * K + kt + (c ^ (r & 3)) * 8;
      gload16(Bh + src, buf + 2048 + rep * 2048 + w * 512);
    }
  };

  floatx4 acc[2][4] = {};
  stage(0, 0);
  __syncthreads();
  int cur = 0;
  for (int kt = 0; kt < K; kt += 32){
    if (kt + 32 < K) stage(kt + 32, cur ^ 1);
    const unsigned short* buf = lds + cur * BUFN;
    short8 a_h[2], b_h[4];
    for (int ms = 0; ms < 2; ms++){
      int r = wr * 32 + ms * 16 + lr;
      int off = r * 32 + ((lg ^ (r & 3)) * 8);
      a_h[ms] = *(const short8*)(buf + off);
    }
    for (int ns = 0; ns < 4; ns++){
      int r = wc * 64 + ns * 16 + lr;
      int off = r * 32 + ((lg ^ (r & 3)) * 8);
      b_h[ns] = *(const short8*)(buf + 2048 + off);
    }
    for (int ms = 0; ms < 2; ms++)
      for (int ns = 0; ns < 4; ns++)
        acc[ms][ns] = MFMA(a_h[ms], b_h[ns], acc[ms][ns], 0, 0, 0);
    __syncthreads();
    cur ^= 1;
  }
  for (int ms = 0; ms < 2; ms++)
    for (int ns = 0; ns < 4; ns++){
      int mrow = m0 + wr * 32 + ms * 16 + lg * 4;
      int ncol = n0 + wc * 64 + ns * 16 + lr;
      for (int rr = 0; rr < 4; rr++){
        float v = acc[ms][ns][rr];
        int o = (mrow + rr) * N + ncol;
        if constexpr (OUT == 1) ((unsigned short*)out0)[o] = f2bf(v);
        else                    ((float*)out0)[o] = v;
      }
    }
}

// ---------------------------------------------------------------------------
// Transpose V [B*S, H*hd] (bf16) -> Vt [B,H,hd,S]   (R3-exact, no kappa)
__global__ __launch_bounds__(256) void k_transpose(const unsigned short* __restrict__ V,
                                                   unsigned short* __restrict__ Vt){
  __shared__ unsigned short t[64][72];
  int tid = threadIdx.x;
  int gx = blockIdx.x;
  int st = gx & 15, bh = gx >> 4;
  int b = bh >> 4, h = bh & 15;
  int s0 = st * 64;
  for (int idx = tid; idx < 512; idx += 256){
    int i = idx >> 3, c = idx & 7;
    short8 v = *(const short8*)(V + (b * 1024 + s0 + i) * 1024 + h * 64 + c * 8);
    *(short8*)(&t[i][c * 8]) = v;
  }
  __syncthreads();
  for (int idx = tid; idx < 512; idx += 256){
    int j = idx >> 3, ci = idx & 7;
    short8 o;
    for (int ii = 0; ii < 8; ii++) o[ii] = (short)t[ci * 8 + ii][j];
    *(short8*)(Vt + (bh * 64 + j) * 1024 + s0 + ci * 8) = o;
  }
}

// ---------------------------------------------------------------------------
// Flash attention (R3-exact). Grid 1024 qt-major. 4 waves x 16 q-rows.
// Double-buffered K_hi/K_lo/V staging via global_load_lds; QK^T split-3x,
// P via LDS, PV plain bf16. fw carries the 1/sqrt(hd) scale.
__global__ __launch_bounds__(256) void k_attn(
    const unsigned short* __restrict__ Qh, const unsigned short* __restrict__ Ql,
    const unsigned short* __restrict__ Kh, const unsigned short* __restrict__ Kl,
    const unsigned short* __restrict__ Vt, unsigned short* __restrict__ Ob){
  __shared__ unsigned short s_k[2][12288];   // per buf: Kh 4096 | Kl 4096 | V 4096
  __shared__ unsigned short s_p[4096];
  int tid = threadIdx.x;
  int w = tid >> 6, l = tid & 63, lg = l >> 4, lr = l & 15;
  int gx = blockIdx.x;
  int bh = gx & 63, qt = gx >> 6;
  int b = bh >> 4, h = bh & 15;
  int q0 = qt * 64;
  int qs = q0 + w * 16;
  int rowb = b * 1024;

  auto stage = [&](int kt, int bufi){
    int k0 = kt * 64;
    unsigned short* buf = s_k[bufi];
    for (int rep = 0; rep < 2; rep++){
      int idx = rep * 256 + tid;
      int r = idx >> 3, c = idx & 7;
      int cs = c ^ (r & 7);
      int srcK = (rowb + k0 + r) * 1024 + h * 64 + cs * 8;
      int srcV = (bh * 64 + r) * 1024 + k0 + cs * 8;
      unsigned short* dst = buf + rep * 2048 + w * 512;
      gload16(Kh + srcK, dst);
      gload16(Kl + srcK, dst + 4096);
      gload16(Vt + srcV, dst + 8192);
    }
  };

  short8 fqh[2], fql[2];
  for (int ds = 0; ds < 2; ds++){
    int off = (rowb + qs + lr) * 1024 + h * 64 + ds * 32 + lg * 8;
    fqh[ds] = *(const short8*)(Qh + off);
    fql[ds] = *(const short8*)(Ql + off);
  }

  floatx4 o_acc[4] = {};
  float m_r[4], l_r[4];
  for (int r = 0; r < 4; r++){ m_r[r] = -__builtin_inff(); l_r[r] = 0.f; }

  int ntile = qt + 1;
  stage(0, 0);
  __syncthreads();
  int cur = 0;
  for (int kt = 0; kt < ntile; kt++){
    int k0 = kt * 64;
    if (kt + 1 < ntile) stage(kt + 1, cur ^ 1);
    const unsigned short* kb = s_k[cur];

    floatx4 sc[4] = {};
    for (int ds = 0; ds < 2; ds++)
      for (int s = 0; s < 4; s++){
        int r = s * 16 + lr;
        int off = r * 64 + (((ds * 4 + lg) ^ (r & 7)) * 8);
        short8 kh_f = *(const short8*)(kb + off);
        short8 kl_f = *(const short8*)(kb + 4096 + off);
        sc[s] = MFMA(fqh[ds], kh_f, sc[s], 0, 0, 0);
        sc[s] = MFMA(fqh[ds], kl_f, sc[s], 0, 0, 0);
        sc[s] = MFMA(fql[ds], kh_f, sc[s], 0, 0, 0);
      }

    if (kt == ntile - 1){
      for (int s = 0; s < 4; s++)
        for (int r = 0; r < 4; r++)
          if (k0 + s * 16 + lr > qs + lg * 4 + r) sc[s][r] = -__builtin_inff();
    }

    float fac[4];
    for (int r = 0; r < 4; r++){
      float v = fmaxf(fmaxf(sc[0][r], sc[1][r]), fmaxf(sc[2][r], sc[3][r]));
      v = fmaxf(v, __shfl_xor(v, 1));
      v = fmaxf(v, __shfl_xor(v, 2));
      v = fmaxf(v, __shfl_xor(v, 4));
      v = fmaxf(v, __shfl_xor(v, 8));
      float mn = fmaxf(m_r[r], v);
      fac[r] = __expf(m_r[r] - mn);
      m_r[r] = mn;
      float ps = 0.f;
      for (int s = 0; s < 4; s++){
        float p = __expf(sc[s][r] - mn);
        sc[s][r] = p;
        ps += p;
      }
      ps += __shfl_xor(ps, 1); ps += __shfl_xor(ps, 2);
      ps += __shfl_xor(ps, 4); ps += __shfl_xor(ps, 8);
      l_r[r] = l_r[r] * fac[r] + ps;
      o_acc[0][r] *= fac[r]; o_acc[1][r] *= fac[r];
      o_acc[2][r] *= fac[r]; o_acc[3][r] *= fac[r];
    }

    for (int s = 0; s < 4; s++)
      for (int r = 0; r < 4; r++){
        int q = lg * 4 + r;
        int byte = ((s * 32 + lr * 2) ^ ((q & 7) << 4));
        s_p[(w * 16 + q) * 64 + (byte >> 1)] = f2bf(sc[s][r]);
      }

    for (int kk = 0; kk < 2; kk++){
      int rq = lr;
      int offp = (w * 16 + rq) * 64 + ((((kk * 64 + lg * 16) ^ ((rq & 7) << 4))) >> 1);
      short8 pa = *(const short8*)(s_p + offp);
      for (int dsb = 0; dsb < 4; dsb++){
        int rv = dsb * 16 + lr;
        int offv = rv * 64 + (((kk * 4 + lg) ^ (rv & 7)) * 8);
        short8 vb = *(const short8*)(kb + 8192 + offv);
        o_acc[dsb] = MFMA(pa, vb, o_acc[dsb], 0, 0, 0);
      }
    }
    __syncthreads();
    cur ^= 1;
  }

  for (int r = 0; r < 4; r++){
    float inv = 1.f / l_r[r];
    for (int dsb = 0; dsb < 4; dsb++){
      float v = o_acc[dsb][r] * inv;
      int q = qs + lg * 4 + r;
      Ob[(rowb + q) * 1024 + h * 64 + dsb * 16 + lr] = f2bf(v);
    }
  }
}

// ---------------------------------------------------------------------------
extern "C" void kernel_launch(void* const* d_in, const int* in_sizes, int n_in,
                              void* d_out, int out_size, void* d_ws, size_t ws_size,
                              hipStream_t stream){
  const float* x  = (const float*)d_in[0];
  const float* Wq = (const float*)d_in[1];
  const float* Wk = (const float*)d_in[2];
  const float* Wv = (const float*)d_in[3];
  const float* Wo = (const float*)d_in[4];
  const float* fr = (const float*)d_in[5];
  const float* pr = (const float*)d_in[6];

  char* ws = (char*)d_ws;
  size_t off = 0;
  auto alloc = [&](size_t bytes) -> char* {
    char* p = ws + off;
    off += (bytes + 255) & ~(size_t)255;
    return p;
  };
  float* fw = (float*)alloc(1024 * sizeof(float));
  float* pw = (float*)alloc(256);
  const size_t WB = (size_t)1024 * 1024 * 2;
  unsigned short* wq_h = (unsigned short*)alloc(WB);
  unsigned short* wq_l = (unsigned short*)alloc(WB);
  unsigned short* wk_h = (unsigned short*)alloc(WB);
  unsigned short* wk_l = (unsigned short*)alloc(WB);
  unsigned short* wv_b = (unsigned short*)alloc(WB);
  unsigned short* wo_b = (unsigned short*)alloc(WB);
  const size_t XB = (size_t)4096 * 1024 * 2;
  unsigned short* x_h = (unsigned short*)alloc(XB);
  unsigned short* x_l = (unsigned short*)alloc(XB);
  unsigned short* q_h = (unsigned short*)alloc(XB);
  unsigned short* q_l = (unsigned short*)alloc(XB);
  unsigned short* k_h = (unsigned short*)alloc(XB);
  unsigned short* k_l = (unsigned short*)alloc(XB);
  unsigned short* v_b = (unsigned short*)alloc(XB);
  unsigned short* vt  = x_h;   // alias: x_h dead after V GEMM
  unsigned short* o_b = x_l;   // alias: x_l dead after fused QK GEMM

  k_prep_fw<<<1, 1024, 0, stream>>>(fr, pr, fw, pw);
  k_prep_w<<<1024, 256, 0, stream>>>(Wq, Wk, Wv, Wo, fw, pw,
                                     wq_h, wq_l, wk_h, wk_l, wv_b, wo_b);
  k_split_x<<<4096, 256, 0, stream>>>(x, x_h, x_l);

  k_gemm_qk<<<1024, 256, 0, stream>>>(x_h, x_l, wq_h, wq_l, wk_h, wk_l,
                                      q_h, q_l, k_h, k_l);
  dim3 gg(8, 64);
  k_gemm<1><<<gg, 256, 0, stream>>>(x_h, wv_b, (void*)v_b, 4096, 1024, 1024);
  k_transpose<<<1024, 256, 0, stream>>>(v_b, vt);
  k_attn<<<1024, 256, 0, stream>>>(q_h, q_l, k_h, k_l, vt, o_b);
  k_gemm<2><<<gg, 256, 0, stream>>>(o_b, wo_b, d_out, 4096, 1024, 1024);
}

// Round 7
// 178.936 us; speedup vs baseline: 1.5358x; 1.0590x over previous
//
#include <hip/hip_runtime.h>

typedef __attribute__((ext_vector_type(8))) short short8;
typedef __attribute__((ext_vector_type(4))) float float4v;
typedef __attribute__((ext_vector_type(4))) float floatx4;
typedef __attribute__((ext_vector_type(4))) unsigned short ushort4v;

#define DEV static __device__ __forceinline__
#define MFMA __builtin_amdgcn_mfma_f32_16x16x32_bf16

DEV unsigned short f2bf(float f){
  unsigned u = __builtin_bit_cast(unsigned, f);
  unsigned r = u + 0x7FFFu + ((u >> 16) & 1u);
  return (unsigned short)(r >> 16);
}
DEV float bf2f(unsigned short h){
  unsigned u = ((unsigned)h) << 16;
  return __builtin_bit_cast(float, u);
}
DEV float softplus_f(float x){
  if (x > 20.f) return x;
  return log1pf(expf(x));
}

DEV void gload16(const void* g, void* l){
  __builtin_amdgcn_global_load_lds(
      (const __attribute__((address_space(1))) unsigned int*)g,
      (__attribute__((address_space(3))) unsigned int*)l, 16, 0, 0);
}

// ---------------------------------------------------------------------------
__global__ void k_prep_fw(const float* __restrict__ freq_raw,
                          const float* __restrict__ pool_raw,
                          float* __restrict__ fw, float* __restrict__ pw){
  __shared__ float s[1024];
  int d = threadIdx.x;
  s[d] = softplus_f(freq_raw[d]);
  __syncthreads();
  for (int off = 1; off < 1024; off <<= 1){
    float t = (d + off < 1024) ? s[d + off] : 0.f;
    __syncthreads();
    s[d] += t;
    __syncthreads();
  }
  fw[d] = s[d];
  if (d < 3) pw[d] = softplus_f((pool_raw[d] + pool_raw[2 - d]) * 0.5f);
}

// ---------------------------------------------------------------------------
// W~q = (fw/8)*W_q hi/lo; W~k = conv3(W_k) hi/lo; plain bf16 W_v, W_o.
__global__ __launch_bounds__(256) void k_prep_w(
    const float* __restrict__ Wq, const float* __restrict__ Wk,
    const float* __restrict__ Wv, const float* __restrict__ Wo,
    const float* __restrict__ fw, const float* __restrict__ pw,
    unsigned short* __restrict__ wq_h, unsigned short* __restrict__ wq_l,
    unsigned short* __restrict__ wk_h, unsigned short* __restrict__ wk_l,
    unsigned short* __restrict__ wv_b, unsigned short* __restrict__ wo_b){
  int idx = blockIdx.x * 256 + threadIdx.x;
  int n  = idx >> 8;
  int k4 = (idx & 255) << 2;
  float p0 = pw[0], p1 = pw[1], p2 = pw[2];
  float f = fw[n] * 0.125f;
  int o = n * 1024 + k4;
  float4v q4 = *(const float4v*)(Wq + o);
  float4v k0v = *(const float4v*)(Wk + o);
  float4v km = {0.f,0.f,0.f,0.f}, kp = {0.f,0.f,0.f,0.f};
  if (n > 0)    km = *(const float4v*)(Wk + o - 1024);
  if (n < 1023) kp = *(const float4v*)(Wk + o + 1024);
  float4v v4 = *(const float4v*)(Wv + o);
  float4v o4 = *(const float4v*)(Wo + o);
  ushort4v qh, ql, kh, kl, vb, ob;
  for (int j = 0; j < 4; j++){
    float wq_ = f * q4[j];
    unsigned short h = f2bf(wq_);
    qh[j] = h; ql[j] = f2bf(wq_ - bf2f(h));
    float wk_ = p0 * km[j] + p1 * k0v[j] + p2 * kp[j];
    h = f2bf(wk_);
    kh[j] = h; kl[j] = f2bf(wk_ - bf2f(h));
    vb[j] = f2bf(v4[j]);
    ob[j] = f2bf(o4[j]);
  }
  *(ushort4v*)(wq_h + o) = qh; *(ushort4v*)(wq_l + o) = ql;
  *(ushort4v*)(wk_h + o) = kh; *(ushort4v*)(wk_l + o) = kl;
  *(ushort4v*)(wv_b + o) = vb; *(ushort4v*)(wo_b + o) = ob;
}

// ---------------------------------------------------------------------------
__global__ __launch_bounds__(256) void k_split_x(const float* __restrict__ x,
                                                 unsigned short* __restrict__ xh,
                                                 unsigned short* __restrict__ xl){
  int idx = blockIdx.x * 256 + threadIdx.x;
  int o = idx * 4;
  float4v v = *(const float4v*)(x + o);
  ushort4v h4, l4;
  for (int j = 0; j < 4; j++){
    unsigned short h = f2bf(v[j]);
    h4[j] = h; l4[j] = f2bf(v[j] - bf2f(h));
  }
  *(ushort4v*)(xh + o) = h4;
  *(ushort4v*)(xl + o) = l4;
}

// ---------------------------------------------------------------------------
// Fused Q+K projection GEMM. BM=64, BN=64, BK=32, 4 waves (2x2, 32x32/matrix).
// Bank-conflict-free swizzle: chunk ^= (r>>1)&3  (2 lanes per bank-set).
__global__ __launch_bounds__(256) void k_gemm_qk(
    const unsigned short* __restrict__ Ah, const unsigned short* __restrict__ Al,
    const unsigned short* __restrict__ Bqh, const unsigned short* __restrict__ Bql,
    const unsigned short* __restrict__ Bkh, const unsigned short* __restrict__ Bkl,
    unsigned short* __restrict__ qh_o, unsigned short* __restrict__ ql_o,
    unsigned short* __restrict__ kh_o, unsigned short* __restrict__ kl_o){
  __shared__ unsigned short lds[2][12288];  // Ah|Al|Bqh|Bql|Bkh|Bkl x 2048 ush
  int tid = threadIdx.x;
  int w = tid >> 6, l = tid & 63, lg = l >> 4, lr = l & 15;
  int wr = w >> 1, wc = w & 1;
  int g = blockIdx.x;
  int mblk = (g & 7) * 8 + ((g >> 3) & 7);
  int nblk = g >> 6;
  int m0 = mblk * 64, n0 = nblk * 64;

  auto stage = [&](int kt, int bufi){
    unsigned short* buf = lds[bufi];
    int r = tid >> 2, c = tid & 3;
    int cs = (c ^ ((r >> 1) & 3)) * 8;
    int srcA = (m0 + r) * 1024 + kt + cs;
    int srcB = (n0 + r) * 1024 + kt + cs;
    unsigned short* dst = buf + w * 512;
    gload16(Ah + srcA, dst);
    gload16(Al + srcA, dst + 2048);
    gload16(Bqh + srcB, dst + 4096);
    gload16(Bql + srcB, dst + 6144);
    gload16(Bkh + srcB, dst + 8192);
    gload16(Bkl + srcB, dst + 10240);
  };

  floatx4 aq[2][2] = {}, ak[2][2] = {};
  stage(0, 0);
  __syncthreads();
  int cur = 0;
  for (int kt = 0; kt < 1024; kt += 32){
    if (kt + 32 < 1024) stage(kt + 32, cur ^ 1);
    const unsigned short* buf = lds[cur];
    short8 a_h[2], a_l[2], bq_h[2], bq_l[2], bk_h[2], bk_l[2];
    for (int ms = 0; ms < 2; ms++){
      int r = wr * 32 + ms * 16 + lr;
      int off = r * 32 + ((lg ^ ((r >> 1) & 3)) * 8);
      a_h[ms] = *(const short8*)(buf + off);
      a_l[ms] = *(const short8*)(buf + 2048 + off);
    }
    for (int ns = 0; ns < 2; ns++){
      int r = wc * 32 + ns * 16 + lr;
      int off = r * 32 + ((lg ^ ((r >> 1) & 3)) * 8);
      bq_h[ns] = *(const short8*)(buf + 4096 + off);
      bq_l[ns] = *(const short8*)(buf + 6144 + off);
      bk_h[ns] = *(const short8*)(buf + 8192 + off);
      bk_l[ns] = *(const short8*)(buf + 10240 + off);
    }
    for (int ms = 0; ms < 2; ms++)
      for (int ns = 0; ns < 2; ns++){
        aq[ms][ns] = MFMA(a_h[ms], bq_h[ns], aq[ms][ns], 0, 0, 0);
        aq[ms][ns] = MFMA(a_h[ms], bq_l[ns], aq[ms][ns], 0, 0, 0);
        aq[ms][ns] = MFMA(a_l[ms], bq_h[ns], aq[ms][ns], 0, 0, 0);
        ak[ms][ns] = MFMA(a_h[ms], bk_h[ns], ak[ms][ns], 0, 0, 0);
        ak[ms][ns] = MFMA(a_h[ms], bk_l[ns], ak[ms][ns], 0, 0, 0);
        ak[ms][ns] = MFMA(a_l[ms], bk_h[ns], ak[ms][ns], 0, 0, 0);
      }
    __syncthreads();
    cur ^= 1;
  }
  for (int ms = 0; ms < 2; ms++)
    for (int ns = 0; ns < 2; ns++){
      int mrow = m0 + wr * 32 + ms * 16 + lg * 4;
      int ncol = n0 + wc * 32 + ns * 16 + lr;
      for (int rr = 0; rr < 4; rr++){
        int o = (mrow + rr) * 1024 + ncol;
        float v = aq[ms][ns][rr];
        unsigned short hh = f2bf(v);
        qh_o[o] = hh; ql_o[o] = f2bf(v - bf2f(hh));
        v = ak[ms][ns][rr];
        hh = f2bf(v);
        kh_o[o] = hh; kl_o[o] = f2bf(v - bf2f(hh));
      }
    }
}

// ---------------------------------------------------------------------------
// Plain GEMM: C[M,N] = A[M,K] @ B[N,K]^T, BM=64, BN=128, BK=32.
// Conflict-free swizzle (r>>1)&3. OUT: 1 = bf16, 2 = fp32.
// Called with A=W_v, B=x to produce V^T in [H*hd][B*S] layout (stride 4096).
template<int OUT>
__global__ __launch_bounds__(256) void k_gemm(
    const unsigned short* __restrict__ Ah, const unsigned short* __restrict__ Bh,
    void* __restrict__ out0, int M, int N, int K){
  constexpr int BUFN = 6144;
  __shared__ unsigned short lds[2 * BUFN];
  int tid = threadIdx.x;
  int w = tid >> 6, l = tid & 63, lg = l >> 4, lr = l & 15;
  int wr = w >> 1, wc = w & 1;
  int n0 = blockIdx.x * 128, m0 = blockIdx.y * 64;

  auto stage = [&](int kt, int bufi){
    unsigned short* buf = lds + bufi * BUFN;
    { int r = tid >> 2, c = tid & 3;
      int src = (m0 + r) * K + kt + (c ^ ((r >> 1) & 3)) * 8;
      gload16(Ah + src, buf + w * 512); }
    for (int rep = 0; rep < 2; rep++){
      int idx = rep * 256 + tid;
      int r = idx >> 2, c = idx & 3;
      int src = (n0 + r) * K + kt + (c ^ ((r >> 1) & 3)) * 8;
      gload16(Bh + src, buf + 2048 + rep * 2048 + w * 512);
    }
  };

  floatx4 acc[2][4] = {};
  stage(0, 0);
  __syncthreads();
  int cur = 0;
  for (int kt = 0; kt < K; kt += 32){
    if (kt + 32 < K) stage(kt + 32, cur ^ 1);
    const unsigned short* buf = lds + cur * BUFN;
    short8 a_h[2], b_h[4];
    for (int ms = 0; ms < 2; ms++){
      int r = wr * 32 + ms * 16 + lr;
      int off = r * 32 + ((lg ^ ((r >> 1) & 3)) * 8);
      a_h[ms] = *(const short8*)(buf + off);
    }
    for (int ns = 0; ns < 4; ns++){
      int r = wc * 64 + ns * 16 + lr;
      int off = r * 32 + ((lg ^ ((r >> 1) & 3)) * 8);
      b_h[ns] = *(const short8*)(buf + 2048 + off);
    }
    for (int ms = 0; ms < 2; ms++)
      for (int ns = 0; ns < 4; ns++)
        acc[ms][ns] = MFMA(a_h[ms], b_h[ns], acc[ms][ns], 0, 0, 0);
    __syncthreads();
    cur ^= 1;
  }
  for (int ms = 0; ms < 2; ms++)
    for (int ns = 0; ns < 4; ns++){
      int mrow = m0 + wr * 32 + ms * 16 + lg * 4;
      int ncol = n0 + wc * 64 + ns * 16 + lr;
      for (int rr = 0; rr < 4; rr++){
        float v = acc[ms][ns][rr];
        int o = (mrow + rr) * N + ncol;
        if constexpr (OUT == 1) ((unsigned short*)out0)[o] = f2bf(v);
        else                    ((float*)out0)[o] = v;
      }
    }
}

// ---------------------------------------------------------------------------
// Flash attention (R5-exact structure + setprio). Vt layout is [H][hd][B][S]
// (channel-major, stride 4096 = ((h*64+d)*4 + b)*1024 + s) as produced by the
// swapped-operand V^T GEMM.
__global__ __launch_bounds__(256) void k_attn(
    const unsigned short* __restrict__ Qh, const unsigned short* __restrict__ Ql,
    const unsigned short* __restrict__ Kh, const unsigned short* __restrict__ Kl,
    const unsigned short* __restrict__ Vt, unsigned short* __restrict__ Ob){
  __shared__ unsigned short s_k[2][12288];   // per buf: Kh 4096 | Kl 4096 | V 4096
  __shared__ unsigned short s_p[4096];
  int tid = threadIdx.x;
  int w = tid >> 6, l = tid & 63, lg = l >> 4, lr = l & 15;
  int gx = blockIdx.x;
  int bh = gx & 63, qt = gx >> 6;
  int b = bh >> 4, h = bh & 15;
  int q0 = qt * 64;
  int qs = q0 + w * 16;
  int rowb = b * 1024;

  auto stage = [&](int kt, int bufi){
    int k0 = kt * 64;
    unsigned short* buf = s_k[bufi];
    for (int rep = 0; rep < 2; rep++){
      int idx = rep * 256 + tid;
      int r = idx >> 3, c = idx & 7;
      int cs = c ^ (r & 7);
      int srcK = (rowb + k0 + r) * 1024 + h * 64 + cs * 8;
      int srcV = ((h * 64 + r) * 4 + b) * 1024 + k0 + cs * 8;   // [H][hd][B][S]
      unsigned short* dst = buf + rep * 2048 + w * 512;
      gload16(Kh + srcK, dst);
      gload16(Kl + srcK, dst + 4096);
      gload16(Vt + srcV, dst + 8192);
    }
  };

  short8 fqh[2], fql[2];
  for (int ds = 0; ds < 2; ds++){
    int off = (rowb + qs + lr) * 1024 + h * 64 + ds * 32 + lg * 8;
    fqh[ds] = *(const short8*)(Qh + off);
    fql[ds] = *(const short8*)(Ql + off);
  }

  floatx4 o_acc[4] = {};
  float m_r[4], l_r[4];
  for (int r = 0; r < 4; r++){ m_r[r] = -__builtin_inff(); l_r[r] = 0.f; }

  int ntile = qt + 1;
  stage(0, 0);
  __syncthreads();
  int cur = 0;
  for (int kt = 0; kt < ntile; kt++){
    int k0 = kt * 64;
    if (kt + 1 < ntile) stage(kt + 1, cur ^ 1);
    const unsigned short* kb = s_k[cur];

    floatx4 sc[4] = {};
    __builtin_amdgcn_s_setprio(1);
    for (int ds = 0; ds < 2; ds++)
      for (int s = 0; s < 4; s++){
        int r = s * 16 + lr;
        int off = r * 64 + (((ds * 4 + lg) ^ (r & 7)) * 8);
        short8 kh_f = *(const short8*)(kb + off);
        short8 kl_f = *(const short8*)(kb + 4096 + off);
        sc[s] = MFMA(fqh[ds], kh_f, sc[s], 0, 0, 0);
        sc[s] = MFMA(fqh[ds], kl_f, sc[s], 0, 0, 0);
        sc[s] = MFMA(fql[ds], kh_f, sc[s], 0, 0, 0);
      }
    __builtin_amdgcn_s_setprio(0);

    if (kt == ntile - 1){
      for (int s = 0; s < 4; s++)
        for (int r = 0; r < 4; r++)
          if (k0 + s * 16 + lr > qs + lg * 4 + r) sc[s][r] = -__builtin_inff();
    }

    float fac[4];
    for (int r = 0; r < 4; r++){
      float v = fmaxf(fmaxf(sc[0][r], sc[1][r]), fmaxf(sc[2][r], sc[3][r]));
      v = fmaxf(v, __shfl_xor(v, 1));
      v = fmaxf(v, __shfl_xor(v, 2));
      v = fmaxf(v, __shfl_xor(v, 4));
      v = fmaxf(v, __shfl_xor(v, 8));
      float mn = fmaxf(m_r[r], v);
      fac[r] = __expf(m_r[r] - mn);
      m_r[r] = mn;
      float ps = 0.f;
      for (int s = 0; s < 4; s++){
        float p = __expf(sc[s][r] - mn);
        sc[s][r] = p;
        ps += p;
      }
      ps += __shfl_xor(ps, 1); ps += __shfl_xor(ps, 2);
      ps += __shfl_xor(ps, 4); ps += __shfl_xor(ps, 8);
      l_r[r] = l_r[r] * fac[r] + ps;
      o_acc[0][r] *= fac[r]; o_acc[1][r] *= fac[r];
      o_acc[2][r] *= fac[r]; o_acc[3][r] *= fac[r];
    }

    for (int s = 0; s < 4; s++)
      for (int r = 0; r < 4; r++){
        int q = lg * 4 + r;
        int byte = ((s * 32 + lr * 2) ^ ((q & 7) << 4));
        s_p[(w * 16 + q) * 64 + (byte >> 1)] = f2bf(sc[s][r]);
      }

    __builtin_amdgcn_s_setprio(1);
    for (int kk = 0; kk < 2; kk++){
      int rq = lr;
      int offp = (w * 16 + rq) * 64 + ((((kk * 64 + lg * 16) ^ ((rq & 7) << 4))) >> 1);
      short8 pa = *(const short8*)(s_p + offp);
      for (int dsb = 0; dsb < 4; dsb++){
        int rv = dsb * 16 + lr;
        int offv = rv * 64 + (((kk * 4 + lg) ^ (rv & 7)) * 8);
        short8 vb = *(const short8*)(kb + 8192 + offv);
        o_acc[dsb] = MFMA(pa, vb, o_acc[dsb], 0, 0, 0);
      }
    }
    __builtin_amdgcn_s_setprio(0);
    __syncthreads();
    cur ^= 1;
  }

  for (int r = 0; r < 4; r++){
    float inv = 1.f / l_r[r];
    for (int dsb = 0; dsb < 4; dsb++){
      float v = o_acc[dsb][r] * inv;
      int q = qs + lg * 4 + r;
      Ob[(rowb + q) * 1024 + h * 64 + dsb * 16 + lr] = f2bf(v);
    }
  }
}

// ---------------------------------------------------------------------------
extern "C" void kernel_launch(void* const* d_in, const int* in_sizes, int n_in,
                              void* d_out, int out_size, void* d_ws, size_t ws_size,
                              hipStream_t stream){
  const float* x  = (const float*)d_in[0];
  const float* Wq = (const float*)d_in[1];
  const float* Wk = (const float*)d_in[2];
  const float* Wv = (const float*)d_in[3];
  const float* Wo = (const float*)d_in[4];
  const float* fr = (const float*)d_in[5];
  const float* pr = (const float*)d_in[6];

  char* ws = (char*)d_ws;
  size_t off = 0;
  auto alloc = [&](size_t bytes) -> char* {
    char* p = ws + off;
    off += (bytes + 255) & ~(size_t)255;
    return p;
  };
  float* fw = (float*)alloc(1024 * sizeof(float));
  float* pw = (float*)alloc(256);
  const size_t WB = (size_t)1024 * 1024 * 2;
  unsigned short* wq_h = (unsigned short*)alloc(WB);
  unsigned short* wq_l = (unsigned short*)alloc(WB);
  unsigned short* wk_h = (unsigned short*)alloc(WB);
  unsigned short* wk_l = (unsigned short*)alloc(WB);
  unsigned short* wv_b = (unsigned short*)alloc(WB);
  unsigned short* wo_b = (unsigned short*)alloc(WB);
  const size_t XB = (size_t)4096 * 1024 * 2;
  unsigned short* x_h = (unsigned short*)alloc(XB);
  unsigned short* x_l = (unsigned short*)alloc(XB);
  unsigned short* q_h = (unsigned short*)alloc(XB);
  unsigned short* q_l = (unsigned short*)alloc(XB);
  unsigned short* k_h = (unsigned short*)alloc(XB);
  unsigned short* k_l = (unsigned short*)alloc(XB);
  unsigned short* vt  = (unsigned short*)alloc(XB);   // V^T [H*hd][B*S]
  unsigned short* o_b = x_l;   // alias: x_l dead after fused QK GEMM

  k_prep_fw<<<1, 1024, 0, stream>>>(fr, pr, fw, pw);
  k_prep_w<<<1024, 256, 0, stream>>>(Wq, Wk, Wv, Wo, fw, pw,
                                     wq_h, wq_l, wk_h, wk_l, wv_b, wo_b);
  k_split_x<<<4096, 256, 0, stream>>>(x, x_h, x_l);

  k_gemm_qk<<<1024, 256, 0, stream>>>(x_h, x_l, wq_h, wq_l, wk_h, wk_l,
                                      q_h, q_l, k_h, k_l);
  // V^T = (x @ Wv^T)^T : A=Wv (M=1024), B=x (N=4096) -> out[channel][token]
  dim3 ggv(32, 16);
  k_gemm<1><<<ggv, 256, 0, stream>>>(wv_b, x_h, (void*)vt, 1024, 4096, 1024);
  k_attn<<<1024, 256, 0, stream>>>(q_h, q_l, k_h, k_l, vt, o_b);
  dim3 ggo(8, 64);
  k_gemm<2><<<ggo, 256, 0, stream>>>(o_b, wo_b, d_out, 4096, 1024, 1024);
}

// Round 8
// 163.458 us; speedup vs baseline: 1.6812x; 1.0947x over previous
//
#include <hip/hip_runtime.h>

typedef __attribute__((ext_vector_type(8))) short short8;
typedef __attribute__((ext_vector_type(4))) float float4v;
typedef __attribute__((ext_vector_type(4))) float floatx4;
typedef __attribute__((ext_vector_type(4))) unsigned short ushort4v;

#define DEV static __device__ __forceinline__
#define MFMA __builtin_amdgcn_mfma_f32_16x16x32_bf16

DEV unsigned short f2bf(float f){
  unsigned u = __builtin_bit_cast(unsigned, f);
  unsigned r = u + 0x7FFFu + ((u >> 16) & 1u);
  return (unsigned short)(r >> 16);
}
DEV float bf2f(unsigned short h){
  unsigned u = ((unsigned)h) << 16;
  return __builtin_bit_cast(float, u);
}
DEV float softplus_f(float x){
  if (x > 20.f) return x;
  return log1pf(expf(x));
}

DEV void gload16(const void* g, void* l){
  __builtin_amdgcn_global_load_lds(
      (const __attribute__((address_space(1))) unsigned int*)g,
      (__attribute__((address_space(3))) unsigned int*)l, 16, 0, 0);
}

// ---------------------------------------------------------------------------
__global__ void k_prep_fw(const float* __restrict__ freq_raw,
                          const float* __restrict__ pool_raw,
                          float* __restrict__ fw, float* __restrict__ pw){
  __shared__ float s[1024];
  int d = threadIdx.x;
  s[d] = softplus_f(freq_raw[d]);
  __syncthreads();
  for (int off = 1; off < 1024; off <<= 1){
    float t = (d + off < 1024) ? s[d + off] : 0.f;
    __syncthreads();
    s[d] += t;
    __syncthreads();
  }
  fw[d] = s[d];
  if (d < 3) pw[d] = softplus_f((pool_raw[d] + pool_raw[2 - d]) * 0.5f);
}

// ---------------------------------------------------------------------------
// W~q = (fw/8)*W_q hi/lo; W~k = conv3(W_k) hi/lo; plain bf16 W_v, W_o.
__global__ __launch_bounds__(256) void k_prep_w(
    const float* __restrict__ Wq, const float* __restrict__ Wk,
    const float* __restrict__ Wv, const float* __restrict__ Wo,
    const float* __restrict__ fw, const float* __restrict__ pw,
    unsigned short* __restrict__ wq_h, unsigned short* __restrict__ wq_l,
    unsigned short* __restrict__ wk_h, unsigned short* __restrict__ wk_l,
    unsigned short* __restrict__ wv_b, unsigned short* __restrict__ wo_b){
  int idx = blockIdx.x * 256 + threadIdx.x;
  int n  = idx >> 8;
  int k4 = (idx & 255) << 2;
  float p0 = pw[0], p1 = pw[1], p2 = pw[2];
  float f = fw[n] * 0.125f;
  int o = n * 1024 + k4;
  float4v q4 = *(const float4v*)(Wq + o);
  float4v k0v = *(const float4v*)(Wk + o);
  float4v km = {0.f,0.f,0.f,0.f}, kp = {0.f,0.f,0.f,0.f};
  if (n > 0)    km = *(const float4v*)(Wk + o - 1024);
  if (n < 1023) kp = *(const float4v*)(Wk + o + 1024);
  float4v v4 = *(const float4v*)(Wv + o);
  float4v o4 = *(const float4v*)(Wo + o);
  ushort4v qh, ql, kh, kl, vb, ob;
  for (int j = 0; j < 4; j++){
    float wq_ = f * q4[j];
    unsigned short h = f2bf(wq_);
    qh[j] = h; ql[j] = f2bf(wq_ - bf2f(h));
    float wk_ = p0 * km[j] + p1 * k0v[j] + p2 * kp[j];
    h = f2bf(wk_);
    kh[j] = h; kl[j] = f2bf(wk_ - bf2f(h));
    vb[j] = f2bf(v4[j]);
    ob[j] = f2bf(o4[j]);
  }
  *(ushort4v*)(wq_h + o) = qh; *(ushort4v*)(wq_l + o) = ql;
  *(ushort4v*)(wk_h + o) = kh; *(ushort4v*)(wk_l + o) = kl;
  *(ushort4v*)(wv_b + o) = vb; *(ushort4v*)(wo_b + o) = ob;
}

// ---------------------------------------------------------------------------
__global__ __launch_bounds__(256) void k_split_x(const float* __restrict__ x,
                                                 unsigned short* __restrict__ xh,
                                                 unsigned short* __restrict__ xl){
  int idx = blockIdx.x * 256 + threadIdx.x;
  int o = idx * 4;
  float4v v = *(const float4v*)(x + o);
  ushort4v h4, l4;
  for (int j = 0; j < 4; j++){
    unsigned short h = f2bf(v[j]);
    h4[j] = h; l4[j] = f2bf(v[j] - bf2f(h));
  }
  *(ushort4v*)(xh + o) = h4;
  *(ushort4v*)(xl + o) = l4;
}

// ---------------------------------------------------------------------------
// Fused Q+K projection GEMM. BM=128, BN=64, BK=32, 4 waves (2x2), wave tile
// 64x32 per output matrix (48 MFMA/wave/K-step). Per K-step: 32KB staged,
// 192 MFMAs (2x the arithmetic intensity of the 64x64 tile). LDS 2x32KB.
// Grid 512, A-resident XCD chunking: each XCD owns 4 consecutive mblks.
// Bank-conflict-free swizzle: chunk ^= (r>>1)&3.
__global__ __launch_bounds__(256) void k_gemm_qk(
    const unsigned short* __restrict__ Ah, const unsigned short* __restrict__ Al,
    const unsigned short* __restrict__ Bqh, const unsigned short* __restrict__ Bql,
    const unsigned short* __restrict__ Bkh, const unsigned short* __restrict__ Bkl,
    unsigned short* __restrict__ qh_o, unsigned short* __restrict__ ql_o,
    unsigned short* __restrict__ kh_o, unsigned short* __restrict__ kl_o){
  // per buffer (ush): Ah[0,4096) Al[4096,8192) Bqh[8192,10240) Bql[10240,12288)
  //                   Bkh[12288,14336) Bkl[14336,16384)
  __shared__ unsigned short lds[2][16384];
  int tid = threadIdx.x;
  int w = tid >> 6, l = tid & 63, lg = l >> 4, lr = l & 15;
  int wr = w >> 1, wc = w & 1;
  int g = blockIdx.x;
  int mblk = (g & 7) * 4 + ((g >> 3) & 3);   // XCD owns 4 consecutive mblks
  int nblk = g >> 5;
  int m0 = mblk * 128, n0 = nblk * 64;

  auto stage = [&](int kt, int bufi){
    unsigned short* buf = lds[bufi];
    // A hi/lo: 512 chunks each, 2 per thread
    for (int rep = 0; rep < 2; rep++){
      int idx = rep * 256 + tid;
      int r = idx >> 2, c = idx & 3;
      int cs = (c ^ ((r >> 1) & 3)) * 8;
      int srcA = (m0 + r) * 1024 + kt + cs;
      unsigned short* dst = buf + rep * 2048 + w * 512;
      gload16(Ah + srcA, dst);
      gload16(Al + srcA, dst + 4096);
    }
    // 4 B panels: 256 chunks each, 1 per thread
    {
      int r = tid >> 2, c = tid & 3;
      int cs = (c ^ ((r >> 1) & 3)) * 8;
      int srcB = (n0 + r) * 1024 + kt + cs;
      unsigned short* dst = buf + 8192 + w * 512;
      gload16(Bqh + srcB, dst);
      gload16(Bql + srcB, dst + 2048);
      gload16(Bkh + srcB, dst + 4096);
      gload16(Bkl + srcB, dst + 6144);
    }
  };

  floatx4 aq[4][2] = {}, ak[4][2] = {};
  stage(0, 0);
  __syncthreads();
  int cur = 0;
  for (int kt = 0; kt < 1024; kt += 32){
    if (kt + 32 < 1024) stage(kt + 32, cur ^ 1);
    const unsigned short* buf = lds[cur];
    short8 a_h[4], a_l[4], bq_h[2], bq_l[2], bk_h[2], bk_l[2];
    for (int ms = 0; ms < 4; ms++){
      int r = wr * 64 + ms * 16 + lr;
      int off = r * 32 + ((lg ^ ((r >> 1) & 3)) * 8);
      a_h[ms] = *(const short8*)(buf + off);
      a_l[ms] = *(const short8*)(buf + 4096 + off);
    }
    for (int ns = 0; ns < 2; ns++){
      int r = wc * 32 + ns * 16 + lr;
      int off = r * 32 + ((lg ^ ((r >> 1) & 3)) * 8);
      bq_h[ns] = *(const short8*)(buf + 8192 + off);
      bq_l[ns] = *(const short8*)(buf + 10240 + off);
      bk_h[ns] = *(const short8*)(buf + 12288 + off);
      bk_l[ns] = *(const short8*)(buf + 14336 + off);
    }
    for (int ms = 0; ms < 4; ms++)
      for (int ns = 0; ns < 2; ns++){
        aq[ms][ns] = MFMA(a_h[ms], bq_h[ns], aq[ms][ns], 0, 0, 0);
        aq[ms][ns] = MFMA(a_h[ms], bq_l[ns], aq[ms][ns], 0, 0, 0);
        aq[ms][ns] = MFMA(a_l[ms], bq_h[ns], aq[ms][ns], 0, 0, 0);
        ak[ms][ns] = MFMA(a_h[ms], bk_h[ns], ak[ms][ns], 0, 0, 0);
        ak[ms][ns] = MFMA(a_h[ms], bk_l[ns], ak[ms][ns], 0, 0, 0);
        ak[ms][ns] = MFMA(a_l[ms], bk_h[ns], ak[ms][ns], 0, 0, 0);
      }
    __syncthreads();
    cur ^= 1;
  }
  for (int ms = 0; ms < 4; ms++)
    for (int ns = 0; ns < 2; ns++){
      int mrow = m0 + wr * 64 + ms * 16 + lg * 4;
      int ncol = n0 + wc * 32 + ns * 16 + lr;
      for (int rr = 0; rr < 4; rr++){
        int o = (mrow + rr) * 1024 + ncol;
        float v = aq[ms][ns][rr];
        unsigned short hh = f2bf(v);
        qh_o[o] = hh; ql_o[o] = f2bf(v - bf2f(hh));
        v = ak[ms][ns][rr];
        hh = f2bf(v);
        kh_o[o] = hh; kl_o[o] = f2bf(v - bf2f(hh));
      }
    }
}

// ---------------------------------------------------------------------------
// Plain GEMM: C[M,N] = A[M,K] @ B[N,K]^T, BM=64, BN=128, BK=32.
// Conflict-free swizzle (r>>1)&3. OUT: 1 = bf16, 2 = fp32.
// Called with A=W_v, B=x to produce V^T in [H*hd][B*S] layout (stride 4096).
template<int OUT>
__global__ __launch_bounds__(256) void k_gemm(
    const unsigned short* __restrict__ Ah, const unsigned short* __restrict__ Bh,
    void* __restrict__ out0, int M, int N, int K){
  constexpr int BUFN = 6144;
  __shared__ unsigned short lds[2 * BUFN];
  int tid = threadIdx.x;
  int w = tid >> 6, l = tid & 63, lg = l >> 4, lr = l & 15;
  int wr = w >> 1, wc = w & 1;
  int n0 = blockIdx.x * 128, m0 = blockIdx.y * 64;

  auto stage = [&](int kt, int bufi){
    unsigned short* buf = lds + bufi * BUFN;
    { int r = tid >> 2, c = tid & 3;
      int src = (m0 + r) * K + kt + (c ^ ((r >> 1) & 3)) * 8;
      gload16(Ah + src, buf + w * 512); }
    for (int rep = 0; rep < 2; rep++){
      int idx = rep * 256 + tid;
      int r = idx >> 2, c = idx & 3;
      int src = (n0 + r) * K + kt + (c ^ ((r >> 1) & 3)) * 8;
      gload16(Bh + src, buf + 2048 + rep * 2048 + w * 512);
    }
  };

  floatx4 acc[2][4] = {};
  stage(0, 0);
  __syncthreads();
  int cur = 0;
  for (int kt = 0; kt < K; kt += 32){
    if (kt + 32 < K) stage(kt + 32, cur ^ 1);
    const unsigned short* buf = lds + cur * BUFN;
    short8 a_h[2], b_h[4];
    for (int ms = 0; ms < 2; ms++){
      int r = wr * 32 + ms * 16 + lr;
      int off = r * 32 + ((lg ^ ((r >> 1) & 3)) * 8);
      a_h[ms] = *(const short8*)(buf + off);
    }
    for (int ns = 0; ns < 4; ns++){
      int r = wc * 64 + ns * 16 + lr;
      int off = r * 32 + ((lg ^ ((r >> 1) & 3)) * 8);
      b_h[ns] = *(const short8*)(buf + 2048 + off);
    }
    for (int ms = 0; ms < 2; ms++)
      for (int ns = 0; ns < 4; ns++)
        acc[ms][ns] = MFMA(a_h[ms], b_h[ns], acc[ms][ns], 0, 0, 0);
    __syncthreads();
    cur ^= 1;
  }
  for (int ms = 0; ms < 2; ms++)
    for (int ns = 0; ns < 4; ns++){
      int mrow = m0 + wr * 32 + ms * 16 + lg * 4;
      int ncol = n0 + wc * 64 + ns * 16 + lr;
      for (int rr = 0; rr < 4; rr++){
        float v = acc[ms][ns][rr];
        int o = (mrow + rr) * N + ncol;
        if constexpr (OUT == 1) ((unsigned short*)out0)[o] = f2bf(v);
        else                    ((float*)out0)[o] = v;
      }
    }
}

// ---------------------------------------------------------------------------
// Flash attention (R7-exact). Vt layout is [H][hd][B][S] (stride 4096,
// addr = ((h*64+d)*4 + b)*1024 + s) as produced by the swapped V^T GEMM.
__global__ __launch_bounds__(256) void k_attn(
    const unsigned short* __restrict__ Qh, const unsigned short* __restrict__ Ql,
    const unsigned short* __restrict__ Kh, const unsigned short* __restrict__ Kl,
    const unsigned short* __restrict__ Vt, unsigned short* __restrict__ Ob){
  __shared__ unsigned short s_k[2][12288];   // per buf: Kh 4096 | Kl 4096 | V 4096
  __shared__ unsigned short s_p[4096];
  int tid = threadIdx.x;
  int w = tid >> 6, l = tid & 63, lg = l >> 4, lr = l & 15;
  int gx = blockIdx.x;
  int bh = gx & 63, qt = gx >> 6;
  int b = bh >> 4, h = bh & 15;
  int q0 = qt * 64;
  int qs = q0 + w * 16;
  int rowb = b * 1024;

  auto stage = [&](int kt, int bufi){
    int k0 = kt * 64;
    unsigned short* buf = s_k[bufi];
    for (int rep = 0; rep < 2; rep++){
      int idx = rep * 256 + tid;
      int r = idx >> 3, c = idx & 7;
      int cs = c ^ (r & 7);
      int srcK = (rowb + k0 + r) * 1024 + h * 64 + cs * 8;
      int srcV = ((h * 64 + r) * 4 + b) * 1024 + k0 + cs * 8;   // [H][hd][B][S]
      unsigned short* dst = buf + rep * 2048 + w * 512;
      gload16(Kh + srcK, dst);
      gload16(Kl + srcK, dst + 4096);
      gload16(Vt + srcV, dst + 8192);
    }
  };

  short8 fqh[2], fql[2];
  for (int ds = 0; ds < 2; ds++){
    int off = (rowb + qs + lr) * 1024 + h * 64 + ds * 32 + lg * 8;
    fqh[ds] = *(const short8*)(Qh + off);
    fql[ds] = *(const short8*)(Ql + off);
  }

  floatx4 o_acc[4] = {};
  float m_r[4], l_r[4];
  for (int r = 0; r < 4; r++){ m_r[r] = -__builtin_inff(); l_r[r] = 0.f; }

  int ntile = qt + 1;
  stage(0, 0);
  __syncthreads();
  int cur = 0;
  for (int kt = 0; kt < ntile; kt++){
    int k0 = kt * 64;
    if (kt + 1 < ntile) stage(kt + 1, cur ^ 1);
    const unsigned short* kb = s_k[cur];

    floatx4 sc[4] = {};
    __builtin_amdgcn_s_setprio(1);
    for (int ds = 0; ds < 2; ds++)
      for (int s = 0; s < 4; s++){
        int r = s * 16 + lr;
        int off = r * 64 + (((ds * 4 + lg) ^ (r & 7)) * 8);
        short8 kh_f = *(const short8*)(kb + off);
        short8 kl_f = *(const short8*)(kb + 4096 + off);
        sc[s] = MFMA(fqh[ds], kh_f, sc[s], 0, 0, 0);
        sc[s] = MFMA(fqh[ds], kl_f, sc[s], 0, 0, 0);
        sc[s] = MFMA(fql[ds], kh_f, sc[s], 0, 0, 0);
      }
    __builtin_amdgcn_s_setprio(0);

    if (kt == ntile - 1){
      for (int s = 0; s < 4; s++)
        for (int r = 0; r < 4; r++)
          if (k0 + s * 16 + lr > qs + lg * 4 + r) sc[s][r] = -__builtin_inff();
    }

    float fac[4];
    for (int r = 0; r < 4; r++){
      float v = fmaxf(fmaxf(sc[0][r], sc[1][r]), fmaxf(sc[2][r], sc[3][r]));
      v = fmaxf(v, __shfl_xor(v, 1));
      v = fmaxf(v, __shfl_xor(v, 2));
      v = fmaxf(v, __shfl_xor(v, 4));
      v = fmaxf(v, __shfl_xor(v, 8));
      float mn = fmaxf(m_r[r], v);
      fac[r] = __expf(m_r[r] - mn);
      m_r[r] = mn;
      float ps = 0.f;
      for (int s = 0; s < 4; s++){
        float p = __expf(sc[s][r] - mn);
        sc[s][r] = p;
        ps += p;
      }
      ps += __shfl_xor(ps, 1); ps += __shfl_xor(ps, 2);
      ps += __shfl_xor(ps, 4); ps += __shfl_xor(ps, 8);
      l_r[r] = l_r[r] * fac[r] + ps;
      o_acc[0][r] *= fac[r]; o_acc[1][r] *= fac[r];
      o_acc[2][r] *= fac[r]; o_acc[3][r] *= fac[r];
    }

    for (int s = 0; s < 4; s++)
      for (int r = 0; r < 4; r++){
        int q = lg * 4 + r;
        int byte = ((s * 32 + lr * 2) ^ ((q & 7) << 4));
        s_p[(w * 16 + q) * 64 + (byte >> 1)] = f2bf(sc[s][r]);
      }

    __builtin_amdgcn_s_setprio(1);
    for (int kk = 0; kk < 2; kk++){
      int rq = lr;
      int offp = (w * 16 + rq) * 64 + ((((kk * 64 + lg * 16) ^ ((rq & 7) << 4))) >> 1);
      short8 pa = *(const short8*)(s_p + offp);
      for (int dsb = 0; dsb < 4; dsb++){
        int rv = dsb * 16 + lr;
        int offv = rv * 64 + (((kk * 4 + lg) ^ (rv & 7)) * 8);
        short8 vb = *(const short8*)(kb + 8192 + offv);
        o_acc[dsb] = MFMA(pa, vb, o_acc[dsb], 0, 0, 0);
      }
    }
    __builtin_amdgcn_s_setprio(0);
    __syncthreads();
    cur ^= 1;
  }

  for (int r = 0; r < 4; r++){
    float inv = 1.f / l_r[r];
    for (int dsb = 0; dsb < 4; dsb++){
      float v = o_acc[dsb][r] * inv;
      int q = qs + lg * 4 + r;
      Ob[(rowb + q) * 1024 + h * 64 + dsb * 16 + lr] = f2bf(v);
    }
  }
}

// ---------------------------------------------------------------------------
extern "C" void kernel_launch(void* const* d_in, const int* in_sizes, int n_in,
                              void* d_out, int out_size, void* d_ws, size_t ws_size,
                              hipStream_t stream){
  const float* x  = (const float*)d_in[0];
  const float* Wq = (const float*)d_in[1];
  const float* Wk = (const float*)d_in[2];
  const float* Wv = (const float*)d_in[3];
  const float* Wo = (const float*)d_in[4];
  const float* fr = (const float*)d_in[5];
  const float* pr = (const float*)d_in[6];

  char* ws = (char*)d_ws;
  size_t off = 0;
  auto alloc = [&](size_t bytes) -> char* {
    char* p = ws + off;
    off += (bytes + 255) & ~(size_t)255;
    return p;
  };
  float* fw = (float*)alloc(1024 * sizeof(float));
  float* pw = (float*)alloc(256);
  const size_t WB = (size_t)1024 * 1024 * 2;
  unsigned short* wq_h = (unsigned short*)alloc(WB);
  unsigned short* wq_l = (unsigned short*)alloc(WB);
  unsigned short* wk_h = (unsigned short*)alloc(WB);
  unsigned short* wk_l = (unsigned short*)alloc(WB);
  unsigned short* wv_b = (unsigned short*)alloc(WB);
  unsigned short* wo_b = (unsigned short*)alloc(WB);
  const size_t XB = (size_t)4096 * 1024 * 2;
  unsigned short* x_h = (unsigned short*)alloc(XB);
  unsigned short* x_l = (unsigned short*)alloc(XB);
  unsigned short* q_h = (unsigned short*)alloc(XB);
  unsigned short* q_l = (unsigned short*)alloc(XB);
  unsigned short* k_h = (unsigned short*)alloc(XB);
  unsigned short* k_l = (unsigned short*)alloc(XB);
  unsigned short* vt  = (unsigned short*)alloc(XB);   // V^T [H*hd][B*S]
  unsigned short* o_b = x_l;   // alias: x_l dead after fused QK GEMM

  k_prep_fw<<<1, 1024, 0, stream>>>(fr, pr, fw, pw);
  k_prep_w<<<1024, 256, 0, stream>>>(Wq, Wk, Wv, Wo, fw, pw,
                                     wq_h, wq_l, wk_h, wk_l, wv_b, wo_b);
  k_split_x<<<4096, 256, 0, stream>>>(x, x_h, x_l);

  k_gemm_qk<<<512, 256, 0, stream>>>(x_h, x_l, wq_h, wq_l, wk_h, wk_l,
                                     q_h, q_l, k_h, k_l);
  // V^T = (x @ Wv^T)^T : A=Wv (M=1024), B=x (N=4096) -> out[channel][token]
  dim3 ggv(32, 16);
  k_gemm<1><<<ggv, 256, 0, stream>>>(wv_b, x_h, (void*)vt, 1024, 4096, 1024);
  k_attn<<<1024, 256, 0, stream>>>(q_h, q_l, k_h, k_l, vt, o_b);
  dim3 ggo(8, 64);
  k_gemm<2><<<ggo, 256, 0, stream>>>(o_b, wo_b, d_out, 4096, 1024, 1024);
}

// Round 9
// 144.831 us; speedup vs baseline: 1.8975x; 1.1286x over previous
//
#include <hip/hip_runtime.h>

typedef __attribute__((ext_vector_type(8))) short short8;
typedef __attribute__((ext_vector_type(4))) float float4v;
typedef __attribute__((ext_vector_type(4))) float floatx4;
typedef __attribute__((ext_vector_type(4))) unsigned short ushort4v;

#define DEV static __device__ __forceinline__
#define MFMA __builtin_amdgcn_mfma_f32_16x16x32_bf16

DEV unsigned short f2bf(float f){
  unsigned u = __builtin_bit_cast(unsigned, f);
  unsigned r = u + 0x7FFFu + ((u >> 16) & 1u);
  return (unsigned short)(r >> 16);
}
DEV float bf2f(unsigned short h){
  unsigned u = ((unsigned)h) << 16;
  return __builtin_bit_cast(float, u);
}
DEV float softplus_f(float x){
  if (x > 20.f) return x;
  return log1pf(expf(x));
}

DEV void gload16(const void* g, void* l){
  __builtin_amdgcn_global_load_lds(
      (const __attribute__((address_space(1))) unsigned int*)g,
      (__attribute__((address_space(3))) unsigned int*)l, 16, 0, 0);
}

// ---------------------------------------------------------------------------
__global__ void k_prep_fw(const float* __restrict__ freq_raw,
                          const float* __restrict__ pool_raw,
                          float* __restrict__ fw, float* __restrict__ pw){
  __shared__ float s[1024];
  int d = threadIdx.x;
  s[d] = softplus_f(freq_raw[d]);
  __syncthreads();
  for (int off = 1; off < 1024; off <<= 1){
    float t = (d + off < 1024) ? s[d + off] : 0.f;
    __syncthreads();
    s[d] += t;
    __syncthreads();
  }
  fw[d] = s[d];
  if (d < 3) pw[d] = softplus_f((pool_raw[d] + pool_raw[2 - d]) * 0.5f);
}

// ---------------------------------------------------------------------------
// W~q = (fw/8)*W_q hi/lo; W~k = conv3(W_k) hi/lo; plain bf16 W_v, W_o.
__global__ __launch_bounds__(256) void k_prep_w(
    const float* __restrict__ Wq, const float* __restrict__ Wk,
    const float* __restrict__ Wv, const float* __restrict__ Wo,
    const float* __restrict__ fw, const float* __restrict__ pw,
    unsigned short* __restrict__ wq_h, unsigned short* __restrict__ wq_l,
    unsigned short* __restrict__ wk_h, unsigned short* __restrict__ wk_l,
    unsigned short* __restrict__ wv_b, unsigned short* __restrict__ wo_b){
  int idx = blockIdx.x * 256 + threadIdx.x;
  int n  = idx >> 8;
  int k4 = (idx & 255) << 2;
  float p0 = pw[0], p1 = pw[1], p2 = pw[2];
  float f = fw[n] * 0.125f;
  int o = n * 1024 + k4;
  float4v q4 = *(const float4v*)(Wq + o);
  float4v k0v = *(const float4v*)(Wk + o);
  float4v km = {0.f,0.f,0.f,0.f}, kp = {0.f,0.f,0.f,0.f};
  if (n > 0)    km = *(const float4v*)(Wk + o - 1024);
  if (n < 1023) kp = *(const float4v*)(Wk + o + 1024);
  float4v v4 = *(const float4v*)(Wv + o);
  float4v o4 = *(const float4v*)(Wo + o);
  ushort4v qh, ql, kh, kl, vb, ob;
  for (int j = 0; j < 4; j++){
    float wq_ = f * q4[j];
    unsigned short h = f2bf(wq_);
    qh[j] = h; ql[j] = f2bf(wq_ - bf2f(h));
    float wk_ = p0 * km[j] + p1 * k0v[j] + p2 * kp[j];
    h = f2bf(wk_);
    kh[j] = h; kl[j] = f2bf(wk_ - bf2f(h));
    vb[j] = f2bf(v4[j]);
    ob[j] = f2bf(o4[j]);
  }
  *(ushort4v*)(wq_h + o) = qh; *(ushort4v*)(wq_l + o) = ql;
  *(ushort4v*)(wk_h + o) = kh; *(ushort4v*)(wk_l + o) = kl;
  *(ushort4v*)(wv_b + o) = vb; *(ushort4v*)(wo_b + o) = ob;
}

// ---------------------------------------------------------------------------
__global__ __launch_bounds__(256) void k_split_x(const float* __restrict__ x,
                                                 unsigned short* __restrict__ xh,
                                                 unsigned short* __restrict__ xl){
  int idx = blockIdx.x * 256 + threadIdx.x;
  int o = idx * 4;
  float4v v = *(const float4v*)(x + o);
  ushort4v h4, l4;
  for (int j = 0; j < 4; j++){
    unsigned short h = f2bf(v[j]);
    h4[j] = h; l4[j] = f2bf(v[j] - bf2f(h));
  }
  *(ushort4v*)(xh + o) = h4;
  *(ushort4v*)(xl + o) = l4;
}

// ---------------------------------------------------------------------------
// Fused Q+K projection GEMM. BM=128, BN=64, BK=32, 4 waves (2x2), wave tile
// 64x32 per output matrix. LDS 2x32KB, grid 512, XCD-chunked mblks.
__global__ __launch_bounds__(256) void k_gemm_qk(
    const unsigned short* __restrict__ Ah, const unsigned short* __restrict__ Al,
    const unsigned short* __restrict__ Bqh, const unsigned short* __restrict__ Bql,
    const unsigned short* __restrict__ Bkh, const unsigned short* __restrict__ Bkl,
    unsigned short* __restrict__ qh_o, unsigned short* __restrict__ ql_o,
    unsigned short* __restrict__ kh_o, unsigned short* __restrict__ kl_o){
  __shared__ unsigned short lds[2][16384];
  int tid = threadIdx.x;
  int w = tid >> 6, l = tid & 63, lg = l >> 4, lr = l & 15;
  int wr = w >> 1, wc = w & 1;
  int g = blockIdx.x;
  int mblk = (g & 7) * 4 + ((g >> 3) & 3);
  int nblk = g >> 5;
  int m0 = mblk * 128, n0 = nblk * 64;

  auto stage = [&](int kt, int bufi){
    unsigned short* buf = lds[bufi];
    for (int rep = 0; rep < 2; rep++){
      int idx = rep * 256 + tid;
      int r = idx >> 2, c = idx & 3;
      int cs = (c ^ ((r >> 1) & 3)) * 8;
      int srcA = (m0 + r) * 1024 + kt + cs;
      unsigned short* dst = buf + rep * 2048 + w * 512;
      gload16(Ah + srcA, dst);
      gload16(Al + srcA, dst + 4096);
    }
    {
      int r = tid >> 2, c = tid & 3;
      int cs = (c ^ ((r >> 1) & 3)) * 8;
      int srcB = (n0 + r) * 1024 + kt + cs;
      unsigned short* dst = buf + 8192 + w * 512;
      gload16(Bqh + srcB, dst);
      gload16(Bql + srcB, dst + 2048);
      gload16(Bkh + srcB, dst + 4096);
      gload16(Bkl + srcB, dst + 6144);
    }
  };

  floatx4 aq[4][2] = {}, ak[4][2] = {};
  stage(0, 0);
  __syncthreads();
  int cur = 0;
  for (int kt = 0; kt < 1024; kt += 32){
    if (kt + 32 < 1024) stage(kt + 32, cur ^ 1);
    const unsigned short* buf = lds[cur];
    short8 a_h[4], a_l[4], bq_h[2], bq_l[2], bk_h[2], bk_l[2];
    for (int ms = 0; ms < 4; ms++){
      int r = wr * 64 + ms * 16 + lr;
      int off = r * 32 + ((lg ^ ((r >> 1) & 3)) * 8);
      a_h[ms] = *(const short8*)(buf + off);
      a_l[ms] = *(const short8*)(buf + 4096 + off);
    }
    for (int ns = 0; ns < 2; ns++){
      int r = wc * 32 + ns * 16 + lr;
      int off = r * 32 + ((lg ^ ((r >> 1) & 3)) * 8);
      bq_h[ns] = *(const short8*)(buf + 8192 + off);
      bq_l[ns] = *(const short8*)(buf + 10240 + off);
      bk_h[ns] = *(const short8*)(buf + 12288 + off);
      bk_l[ns] = *(const short8*)(buf + 14336 + off);
    }
    for (int ms = 0; ms < 4; ms++)
      for (int ns = 0; ns < 2; ns++){
        aq[ms][ns] = MFMA(a_h[ms], bq_h[ns], aq[ms][ns], 0, 0, 0);
        aq[ms][ns] = MFMA(a_h[ms], bq_l[ns], aq[ms][ns], 0, 0, 0);
        aq[ms][ns] = MFMA(a_l[ms], bq_h[ns], aq[ms][ns], 0, 0, 0);
        ak[ms][ns] = MFMA(a_h[ms], bk_h[ns], ak[ms][ns], 0, 0, 0);
        ak[ms][ns] = MFMA(a_h[ms], bk_l[ns], ak[ms][ns], 0, 0, 0);
        ak[ms][ns] = MFMA(a_l[ms], bk_h[ns], ak[ms][ns], 0, 0, 0);
      }
    __syncthreads();
    cur ^= 1;
  }
  for (int ms = 0; ms < 4; ms++)
    for (int ns = 0; ns < 2; ns++){
      int mrow = m0 + wr * 64 + ms * 16 + lg * 4;
      int ncol = n0 + wc * 32 + ns * 16 + lr;
      for (int rr = 0; rr < 4; rr++){
        int o = (mrow + rr) * 1024 + ncol;
        float v = aq[ms][ns][rr];
        unsigned short hh = f2bf(v);
        qh_o[o] = hh; ql_o[o] = f2bf(v - bf2f(hh));
        v = ak[ms][ns][rr];
        hh = f2bf(v);
        kh_o[o] = hh; kl_o[o] = f2bf(v - bf2f(hh));
      }
    }
}

// ---------------------------------------------------------------------------
// Plain GEMM: C[M,N] = A[M,K] @ B[N,K]^T, BM=64, BN=128, BK=32.
// OUT: 1 = bf16, 2 = fp32, 3 = bf16 with kappa^-1 column scramble (for V^T:
// physical token slot p = (ns>>1)*32 + (lr>>2)*8 + (ns&1)*4 + (lr&3) within
// each 64-token group, so attention's in-register P^T packing pairs with
// contiguous V chunks).
template<int OUT>
__global__ __launch_bounds__(256) void k_gemm(
    const unsigned short* __restrict__ Ah, const unsigned short* __restrict__ Bh,
    void* __restrict__ out0, int M, int N, int K){
  constexpr int BUFN = 6144;
  __shared__ unsigned short lds[2 * BUFN];
  int tid = threadIdx.x;
  int w = tid >> 6, l = tid & 63, lg = l >> 4, lr = l & 15;
  int wr = w >> 1, wc = w & 1;
  int n0 = blockIdx.x * 128, m0 = blockIdx.y * 64;

  auto stage = [&](int kt, int bufi){
    unsigned short* buf = lds + bufi * BUFN;
    { int r = tid >> 2, c = tid & 3;
      int src = (m0 + r) * K + kt + (c ^ ((r >> 1) & 3)) * 8;
      gload16(Ah + src, buf + w * 512); }
    for (int rep = 0; rep < 2; rep++){
      int idx = rep * 256 + tid;
      int r = idx >> 2, c = idx & 3;
      int src = (n0 + r) * K + kt + (c ^ ((r >> 1) & 3)) * 8;
      gload16(Bh + src, buf + 2048 + rep * 2048 + w * 512);
    }
  };

  floatx4 acc[2][4] = {};
  stage(0, 0);
  __syncthreads();
  int cur = 0;
  for (int kt = 0; kt < K; kt += 32){
    if (kt + 32 < K) stage(kt + 32, cur ^ 1);
    const unsigned short* buf = lds + cur * BUFN;
    short8 a_h[2], b_h[4];
    for (int ms = 0; ms < 2; ms++){
      int r = wr * 32 + ms * 16 + lr;
      int off = r * 32 + ((lg ^ ((r >> 1) & 3)) * 8);
      a_h[ms] = *(const short8*)(buf + off);
    }
    for (int ns = 0; ns < 4; ns++){
      int r = wc * 64 + ns * 16 + lr;
      int off = r * 32 + ((lg ^ ((r >> 1) & 3)) * 8);
      b_h[ns] = *(const short8*)(buf + 2048 + off);
    }
    for (int ms = 0; ms < 2; ms++)
      for (int ns = 0; ns < 4; ns++)
        acc[ms][ns] = MFMA(a_h[ms], b_h[ns], acc[ms][ns], 0, 0, 0);
    __syncthreads();
    cur ^= 1;
  }
  for (int ms = 0; ms < 2; ms++)
    for (int ns = 0; ns < 4; ns++){
      int mrow = m0 + wr * 32 + ms * 16 + lg * 4;
      int ncol;
      if constexpr (OUT == 3){
        int p = ((ns >> 1) << 5) | ((lr >> 2) << 3) | ((ns & 1) << 2) | (lr & 3);
        ncol = n0 + wc * 64 + p;
      } else {
        ncol = n0 + wc * 64 + ns * 16 + lr;
      }
      for (int rr = 0; rr < 4; rr++){
        float v = acc[ms][ns][rr];
        int o = (mrow + rr) * N + ncol;
        if constexpr (OUT == 2) ((float*)out0)[o] = v;
        else                    ((unsigned short*)out0)[o] = f2bf(v);
      }
    }
}

// ---------------------------------------------------------------------------
// Flash attention, swapped-operand on the R8 skeleton. Grid 1024 qt-major,
// 4 waves x 16 q-rows, double-buffered K_hi/K_lo/V staging (48 KB, 3 blk/CU).
// scores^T = mfma(A=K, B=Q): lane owns q = qs+lane&15; softmax in-lane +
// 4 shuffles; P^T packs in-register as PV's B-operand (no P LDS round trip);
// V is kappa-permuted at the V^T GEMM epilogue so PV A-frags read contiguous.
// Vt layout: [H][hd][B][S_kappa], addr = ((h*64+d)*4 + b)*1024 + s_phys.
__global__ __launch_bounds__(256) void k_attn(
    const unsigned short* __restrict__ Qh, const unsigned short* __restrict__ Ql,
    const unsigned short* __restrict__ Kh, const unsigned short* __restrict__ Kl,
    const unsigned short* __restrict__ Vt, unsigned short* __restrict__ Ob){
  __shared__ unsigned short s_k[2][12288];   // per buf: Kh 4096 | Kl 4096 | V 4096
  int tid = threadIdx.x;
  int w = tid >> 6, l = tid & 63, lg = l >> 4, lr = l & 15;
  int gx = blockIdx.x;
  int bh = gx & 63, qt = gx >> 6;
  int b = bh >> 4, h = bh & 15;
  int q0 = qt * 64;
  int qs = q0 + w * 16;
  int rowb = b * 1024;

  auto stage = [&](int kt, int bufi){
    int k0 = kt * 64;
    unsigned short* buf = s_k[bufi];
    for (int rep = 0; rep < 2; rep++){
      int idx = rep * 256 + tid;
      int r = idx >> 3, c = idx & 7;
      int cs = c ^ (r & 7);
      int srcK = (rowb + k0 + r) * 1024 + h * 64 + cs * 8;
      int srcV = ((h * 64 + r) * 4 + b) * 1024 + k0 + cs * 8;
      unsigned short* dst = buf + rep * 2048 + w * 512;
      gload16(Kh + srcK, dst);
      gload16(Kl + srcK, dst + 4096);
      gload16(Vt + srcV, dst + 8192);
    }
  };

  // Q fragments (B-operand now; load addresses identical to R8)
  short8 fqh[2], fql[2];
  for (int ds = 0; ds < 2; ds++){
    int off = (rowb + qs + lr) * 1024 + h * 64 + ds * 32 + lg * 8;
    fqh[ds] = *(const short8*)(Qh + off);
    fql[ds] = *(const short8*)(Ql + off);
  }

  floatx4 oT[4] = {};      // O^T: col q = lr, row d = dsb*16 + 4*lg + rr
  float m_r = -__builtin_inff(), l_r = 0.f;   // per-lane q = qs + lr

  int ntile = qt + 1;
  stage(0, 0);
  __syncthreads();
  int cur = 0;
  for (int kt = 0; kt < ntile; kt++){
    int k0 = kt * 64;
    if (kt + 1 < ntile) stage(kt + 1, cur ^ 1);
    const unsigned short* kb = s_k[cur];

    // QK^T swapped: sc[s] cols = q (lr), rows = key k0 + s*16 + 4*lg + rr
    floatx4 sc[4] = {};
    __builtin_amdgcn_s_setprio(1);
    for (int ds = 0; ds < 2; ds++)
      for (int s = 0; s < 4; s++){
        int r = s * 16 + lr;
        int off = r * 64 + (((ds * 4 + lg) ^ (r & 7)) * 8);
        short8 kh_f = *(const short8*)(kb + off);
        short8 kl_f = *(const short8*)(kb + 4096 + off);
        sc[s] = MFMA(kh_f, fqh[ds], sc[s], 0, 0, 0);
        sc[s] = MFMA(kl_f, fqh[ds], sc[s], 0, 0, 0);
        sc[s] = MFMA(kh_f, fql[ds], sc[s], 0, 0, 0);
      }
    __builtin_amdgcn_s_setprio(0);

    if (kt == ntile - 1){
      #pragma unroll
      for (int s = 0; s < 4; s++)
        #pragma unroll
        for (int rr = 0; rr < 4; rr++)
          if (k0 + s * 16 + 4 * lg + rr > qs + lr) sc[s][rr] = -__builtin_inff();
    }

    // online softmax: per-lane q-row (16 in-lane values; lanes l, l^16, l^32
    // share the same q -> xor16 + xor32 combine)
    float mx = sc[0][0];
    #pragma unroll
    for (int s = 0; s < 4; s++)
      #pragma unroll
      for (int rr = 0; rr < 4; rr++) mx = fmaxf(mx, sc[s][rr]);
    mx = fmaxf(mx, __shfl_xor(mx, 16));
    mx = fmaxf(mx, __shfl_xor(mx, 32));
    float mn = fmaxf(m_r, mx);
    float fac = __expf(m_r - mn);
    m_r = mn;
    float ps = 0.f;
    #pragma unroll
    for (int s = 0; s < 4; s++)
      #pragma unroll
      for (int rr = 0; rr < 4; rr++){
        float p = __expf(sc[s][rr] - mn);
        sc[s][rr] = p;
        ps += p;
      }
    ps += __shfl_xor(ps, 16);
    ps += __shfl_xor(ps, 32);
    l_r = l_r * fac + ps;
    #pragma unroll
    for (int dsb = 0; dsb < 4; dsb++) oT[dsb] *= fac;

    // PV: oT += mfma(A = V_kappa from LDS, B = P^T packed in-register)
    __builtin_amdgcn_s_setprio(1);
    #pragma unroll
    for (int kk = 0; kk < 2; kk++){
      short8 pb;
      #pragma unroll
      for (int j = 0; j < 8; j++)
        pb[j] = (short)f2bf(sc[2 * kk + (j >> 2)][j & 3]);
      #pragma unroll
      for (int dsb = 0; dsb < 4; dsb++){
        int rv = dsb * 16 + lr;
        int offv = rv * 64 + (((kk * 4 + lg) ^ (rv & 7)) * 8);
        short8 vb = *(const short8*)(kb + 8192 + offv);
        oT[dsb] = MFMA(vb, pb, oT[dsb], 0, 0, 0);
      }
    }
    __builtin_amdgcn_s_setprio(0);
    __syncthreads();
    cur ^= 1;
  }

  float inv = 1.f / l_r;
  int base = (rowb + qs + lr) * 1024 + h * 64;
  #pragma unroll
  for (int dsb = 0; dsb < 4; dsb++){
    ushort4v o4;
    #pragma unroll
    for (int rr = 0; rr < 4; rr++) o4[rr] = f2bf(oT[dsb][rr] * inv);
    *(ushort4v*)(Ob + base + dsb * 16 + 4 * lg) = o4;
  }
}

// ---------------------------------------------------------------------------
extern "C" void kernel_launch(void* const* d_in, const int* in_sizes, int n_in,
                              void* d_out, int out_size, void* d_ws, size_t ws_size,
                              hipStream_t stream){
  const float* x  = (const float*)d_in[0];
  const float* Wq = (const float*)d_in[1];
  const float* Wk = (const float*)d_in[2];
  const float* Wv = (const float*)d_in[3];
  const float* Wo = (const float*)d_in[4];
  const float* fr = (const float*)d_in[5];
  const float* pr = (const float*)d_in[6];

  char* ws = (char*)d_ws;
  size_t off = 0;
  auto alloc = [&](size_t bytes) -> char* {
    char* p = ws + off;
    off += (bytes + 255) & ~(size_t)255;
    return p;
  };
  float* fw = (float*)alloc(1024 * sizeof(float));
  float* pw = (float*)alloc(256);
  const size_t WB = (size_t)1024 * 1024 * 2;
  unsigned short* wq_h = (unsigned short*)alloc(WB);
  unsigned short* wq_l = (unsigned short*)alloc(WB);
  unsigned short* wk_h = (unsigned short*)alloc(WB);
  unsigned short* wk_l = (unsigned short*)alloc(WB);
  unsigned short* wv_b = (unsigned short*)alloc(WB);
  unsigned short* wo_b = (unsigned short*)alloc(WB);
  const size_t XB = (size_t)4096 * 1024 * 2;
  unsigned short* x_h = (unsigned short*)alloc(XB);
  unsigned short* x_l = (unsigned short*)alloc(XB);
  unsigned short* q_h = (unsigned short*)alloc(XB);
  unsigned short* q_l = (unsigned short*)alloc(XB);
  unsigned short* k_h = (unsigned short*)alloc(XB);
  unsigned short* k_l = (unsigned short*)alloc(XB);
  unsigned short* vt  = (unsigned short*)alloc(XB);   // V^T [H*hd][B*S_kappa]
  unsigned short* o_b = x_l;   // alias: x_l dead after fused QK GEMM

  k_prep_fw<<<1, 1024, 0, stream>>>(fr, pr, fw, pw);
  k_prep_w<<<1024, 256, 0, stream>>>(Wq, Wk, Wv, Wo, fw, pw,
                                     wq_h, wq_l, wk_h, wk_l, wv_b, wo_b);
  k_split_x<<<4096, 256, 0, stream>>>(x, x_h, x_l);

  k_gemm_qk<<<512, 256, 0, stream>>>(x_h, x_l, wq_h, wq_l, wk_h, wk_l,
                                     q_h, q_l, k_h, k_l);
  // V^T = (x @ Wv^T)^T with kappa^-1 token scramble per 64-group
  dim3 ggv(32, 16);
  k_gemm<3><<<ggv, 256, 0, stream>>>(wv_b, x_h, (void*)vt, 1024, 4096, 1024);
  k_attn<<<1024, 256, 0, stream>>>(q_h, q_l, k_h, k_l, vt, o_b);
  dim3 ggo(8, 64);
  k_gemm<2><<<ggo, 256, 0, stream>>>(o_b, wo_b, d_out, 4096, 1024, 1024);
}

// Round 10
// 142.895 us; speedup vs baseline: 1.9232x; 1.0135x over previous
//
#include <hip/hip_runtime.h>

typedef __attribute__((ext_vector_type(8))) short short8;
typedef __attribute__((ext_vector_type(4))) float float4v;
typedef __attribute__((ext_vector_type(4))) float floatx4;
typedef __attribute__((ext_vector_type(4))) unsigned short ushort4v;

#define DEV static __device__ __forceinline__
#define MFMA __builtin_amdgcn_mfma_f32_16x16x32_bf16

DEV unsigned short f2bf(float f){
  unsigned u = __builtin_bit_cast(unsigned, f);
  unsigned r = u + 0x7FFFu + ((u >> 16) & 1u);
  return (unsigned short)(r >> 16);
}
DEV float bf2f(unsigned short h){
  unsigned u = ((unsigned)h) << 16;
  return __builtin_bit_cast(float, u);
}
DEV float softplus_f(float x){
  if (x > 20.f) return x;
  return log1pf(expf(x));
}

DEV void gload16(const void* g, void* l){
  __builtin_amdgcn_global_load_lds(
      (const __attribute__((address_space(1))) unsigned int*)g,
      (__attribute__((address_space(3))) unsigned int*)l, 16, 0, 0);
}

// ---------------------------------------------------------------------------
__global__ void k_prep_fw(const float* __restrict__ freq_raw,
                          const float* __restrict__ pool_raw,
                          float* __restrict__ fw, float* __restrict__ pw){
  __shared__ float s[1024];
  int d = threadIdx.x;
  s[d] = softplus_f(freq_raw[d]);
  __syncthreads();
  for (int off = 1; off < 1024; off <<= 1){
    float t = (d + off < 1024) ? s[d + off] : 0.f;
    __syncthreads();
    s[d] += t;
    __syncthreads();
  }
  fw[d] = s[d];
  if (d < 3) pw[d] = softplus_f((pool_raw[d] + pool_raw[2 - d]) * 0.5f);
}

// ---------------------------------------------------------------------------
// W~q = (fw/8)*W_q hi/lo; W~k = conv3(W_k) hi/lo; plain bf16 W_v, W_o.
__global__ __launch_bounds__(256) void k_prep_w(
    const float* __restrict__ Wq, const float* __restrict__ Wk,
    const float* __restrict__ Wv, const float* __restrict__ Wo,
    const float* __restrict__ fw, const float* __restrict__ pw,
    unsigned short* __restrict__ wq_h, unsigned short* __restrict__ wq_l,
    unsigned short* __restrict__ wk_h, unsigned short* __restrict__ wk_l,
    unsigned short* __restrict__ wv_b, unsigned short* __restrict__ wo_b){
  int idx = blockIdx.x * 256 + threadIdx.x;
  int n  = idx >> 8;
  int k4 = (idx & 255) << 2;
  float p0 = pw[0], p1 = pw[1], p2 = pw[2];
  float f = fw[n] * 0.125f;
  int o = n * 1024 + k4;
  float4v q4 = *(const float4v*)(Wq + o);
  float4v k0v = *(const float4v*)(Wk + o);
  float4v km = {0.f,0.f,0.f,0.f}, kp = {0.f,0.f,0.f,0.f};
  if (n > 0)    km = *(const float4v*)(Wk + o - 1024);
  if (n < 1023) kp = *(const float4v*)(Wk + o + 1024);
  float4v v4 = *(const float4v*)(Wv + o);
  float4v o4 = *(const float4v*)(Wo + o);
  ushort4v qh, ql, kh, kl, vb, ob;
  for (int j = 0; j < 4; j++){
    float wq_ = f * q4[j];
    unsigned short h = f2bf(wq_);
    qh[j] = h; ql[j] = f2bf(wq_ - bf2f(h));
    float wk_ = p0 * km[j] + p1 * k0v[j] + p2 * kp[j];
    h = f2bf(wk_);
    kh[j] = h; kl[j] = f2bf(wk_ - bf2f(h));
    vb[j] = f2bf(v4[j]);
    ob[j] = f2bf(o4[j]);
  }
  *(ushort4v*)(wq_h + o) = qh; *(ushort4v*)(wq_l + o) = ql;
  *(ushort4v*)(wk_h + o) = kh; *(ushort4v*)(wk_l + o) = kl;
  *(ushort4v*)(wv_b + o) = vb; *(ushort4v*)(wo_b + o) = ob;
}

// ---------------------------------------------------------------------------
__global__ __launch_bounds__(256) void k_split_x(const float* __restrict__ x,
                                                 unsigned short* __restrict__ xh,
                                                 unsigned short* __restrict__ xl){
  int idx = blockIdx.x * 256 + threadIdx.x;
  int o = idx * 4;
  float4v v = *(const float4v*)(x + o);
  ushort4v h4, l4;
  for (int j = 0; j < 4; j++){
    unsigned short h = f2bf(v[j]);
    h4[j] = h; l4[j] = f2bf(v[j] - bf2f(h));
  }
  *(ushort4v*)(xh + o) = h4;
  *(ushort4v*)(xl + o) = l4;
}

// ---------------------------------------------------------------------------
// Fused Q+K projection GEMM. BM=128, BN=64, BK=32, 512 threads (8 waves,
// 2x4 wave grid, wave tile 64x16 per output matrix). 3-buffer LDS ring
// (3x32KB) with counted s_waitcnt vmcnt(N) + raw s_barrier: the wait in
// iteration t targets stage(t) issued two iterations earlier, so load
// latency is fully hidden (no vmcnt(0) drain in the main loop).
__global__ __launch_bounds__(512) void k_gemm_qk(
    const unsigned short* __restrict__ Ah, const unsigned short* __restrict__ Al,
    const unsigned short* __restrict__ Bqh, const unsigned short* __restrict__ Bql,
    const unsigned short* __restrict__ Bkh, const unsigned short* __restrict__ Bkl,
    unsigned short* __restrict__ qh_o, unsigned short* __restrict__ ql_o,
    unsigned short* __restrict__ kh_o, unsigned short* __restrict__ kl_o){
  // per buffer (ush): Ah[0,4096) Al[4096,8192) Bqh[8192,10240) Bql[10240,12288)
  //                   Bkh[12288,14336) Bkl[14336,16384)
  __shared__ unsigned short lds[3][16384];
  int tid = threadIdx.x;
  int w = tid >> 6, l = tid & 63, lg = l >> 4, lr = l & 15;
  int wr = w >> 2, wc = w & 3;
  int g = blockIdx.x;
  int mblk = (g & 7) * 4 + ((g >> 3) & 3);   // XCD owns 4 consecutive mblks
  int nblk = g >> 5;
  int m0 = mblk * 128, n0 = nblk * 64;

  // per-wave-uniform B panel pointers (waves 0-3 handle hi, 4-7 lo)
  const unsigned short* Bp0 = (w < 4) ? Bqh : Bql;
  const unsigned short* Bp1 = (w < 4) ? Bkh : Bkl;

  auto stage = [&](int kt, int bufi){
    unsigned short* buf = lds[bufi];
    {   // A hi/lo: 512 chunks per component, 1 per thread each
      int r = tid >> 2, c = tid & 3;
      int cs = (c ^ ((r >> 1) & 3)) * 8;
      int srcA = (m0 + r) * 1024 + kt + cs;
      gload16(Ah + srcA, buf + w * 512);
      gload16(Al + srcA, buf + 4096 + w * 512);
    }
    {   // B: 4 panels x 256 chunks; thread covers chunk tid and tid+512
      int within = tid & 255;
      int r = within >> 2, c = within & 3;
      int cs = (c ^ ((r >> 1) & 3)) * 8;
      int srcB = (n0 + r) * 1024 + kt + cs;
      gload16(Bp0 + srcB, buf + 8192 + w * 512);
      gload16(Bp1 + srcB, buf + 12288 + w * 512);
    }
  };

  floatx4 aq[4] = {}, ak[4] = {};
  stage(0, 0);
  stage(32, 1);
  for (int t = 0; t < 32; ++t){
    if (t == 31) asm volatile("s_waitcnt vmcnt(0)" ::: "memory");
    else         asm volatile("s_waitcnt vmcnt(4)" ::: "memory");
    __builtin_amdgcn_sched_barrier(0);
    __builtin_amdgcn_s_barrier();
    __builtin_amdgcn_sched_barrier(0);
    if (t + 2 < 32) stage((t + 2) * 32, (t + 2) % 3);

    const unsigned short* buf = lds[t % 3];
    short8 a_h[4], a_l[4];
    #pragma unroll
    for (int ms = 0; ms < 4; ms++){
      int r = wr * 64 + ms * 16 + lr;
      int off = r * 32 + ((lg ^ ((r >> 1) & 3)) * 8);
      a_h[ms] = *(const short8*)(buf + off);
      a_l[ms] = *(const short8*)(buf + 4096 + off);
    }
    int rb = wc * 16 + lr;
    int offb = rb * 32 + ((lg ^ ((rb >> 1) & 3)) * 8);
    short8 bq_h = *(const short8*)(buf + 8192 + offb);
    short8 bq_l = *(const short8*)(buf + 10240 + offb);
    short8 bk_h = *(const short8*)(buf + 12288 + offb);
    short8 bk_l = *(const short8*)(buf + 14336 + offb);
    // 3 dependency-free passes (dep distance 8 per accumulator)
    #pragma unroll
    for (int ms = 0; ms < 4; ms++){
      aq[ms] = MFMA(a_h[ms], bq_h, aq[ms], 0, 0, 0);
      ak[ms] = MFMA(a_h[ms], bk_h, ak[ms], 0, 0, 0);
    }
    #pragma unroll
    for (int ms = 0; ms < 4; ms++){
      aq[ms] = MFMA(a_h[ms], bq_l, aq[ms], 0, 0, 0);
      ak[ms] = MFMA(a_h[ms], bk_l, ak[ms], 0, 0, 0);
    }
    #pragma unroll
    for (int ms = 0; ms < 4; ms++){
      aq[ms] = MFMA(a_l[ms], bq_h, aq[ms], 0, 0, 0);
      ak[ms] = MFMA(a_l[ms], bk_h, ak[ms], 0, 0, 0);
    }
  }

  for (int ms = 0; ms < 4; ms++){
    int mrow = m0 + wr * 64 + ms * 16 + lg * 4;
    int ncol = n0 + wc * 16 + lr;
    for (int rr = 0; rr < 4; rr++){
      int o = (mrow + rr) * 1024 + ncol;
      float v = aq[ms][rr];
      unsigned short hh = f2bf(v);
      qh_o[o] = hh; ql_o[o] = f2bf(v - bf2f(hh));
      v = ak[ms][rr];
      hh = f2bf(v);
      kh_o[o] = hh; kl_o[o] = f2bf(v - bf2f(hh));
    }
  }
}

// ---------------------------------------------------------------------------
// Plain GEMM: C[M,N] = A[M,K] @ B[N,K]^T, BM=64, BN=128, BK=32, 4 waves.
// 3-buffer LDS ring + counted vmcnt (same pipeline as k_gemm_qk).
// OUT: 1 = bf16, 2 = fp32, 3 = bf16 with kappa^-1 column scramble (V^T).
template<int OUT>
__global__ __launch_bounds__(256) void k_gemm(
    const unsigned short* __restrict__ Ah, const unsigned short* __restrict__ Bh,
    void* __restrict__ out0, int M, int N, int K){
  constexpr int BUFN = 6144;
  __shared__ unsigned short lds[3 * BUFN];
  int tid = threadIdx.x;
  int w = tid >> 6, l = tid & 63, lg = l >> 4, lr = l & 15;
  int wr = w >> 1, wc = w & 1;
  int n0 = blockIdx.x * 128, m0 = blockIdx.y * 64;

  auto stage = [&](int kt, int bufi){
    unsigned short* buf = lds + bufi * BUFN;
    { int r = tid >> 2, c = tid & 3;
      int src = (m0 + r) * K + kt + (c ^ ((r >> 1) & 3)) * 8;
      gload16(Ah + src, buf + w * 512); }
    for (int rep = 0; rep < 2; rep++){
      int idx = rep * 256 + tid;
      int r = idx >> 2, c = idx & 3;
      int src = (n0 + r) * K + kt + (c ^ ((r >> 1) & 3)) * 8;
      gload16(Bh + src, buf + 2048 + rep * 2048 + w * 512);
    }
  };

  floatx4 acc[2][4] = {};
  int nT = K >> 5;
  stage(0, 0);
  stage(32, 1);
  for (int t = 0; t < nT; ++t){
    if (t == nT - 1) asm volatile("s_waitcnt vmcnt(0)" ::: "memory");
    else             asm volatile("s_waitcnt vmcnt(3)" ::: "memory");
    __builtin_amdgcn_sched_barrier(0);
    __builtin_amdgcn_s_barrier();
    __builtin_amdgcn_sched_barrier(0);
    if (t + 2 < nT) stage((t + 2) * 32, (t + 2) % 3);

    const unsigned short* buf = lds + (t % 3) * BUFN;
    short8 a_h[2], b_h[4];
    #pragma unroll
    for (int ms = 0; ms < 2; ms++){
      int r = wr * 32 + ms * 16 + lr;
      int off = r * 32 + ((lg ^ ((r >> 1) & 3)) * 8);
      a_h[ms] = *(const short8*)(buf + off);
    }
    #pragma unroll
    for (int ns = 0; ns < 4; ns++){
      int r = wc * 64 + ns * 16 + lr;
      int off = r * 32 + ((lg ^ ((r >> 1) & 3)) * 8);
      b_h[ns] = *(const short8*)(buf + 2048 + off);
    }
    #pragma unroll
    for (int ms = 0; ms < 2; ms++)
      #pragma unroll
      for (int ns = 0; ns < 4; ns++)
        acc[ms][ns] = MFMA(a_h[ms], b_h[ns], acc[ms][ns], 0, 0, 0);
  }
  for (int ms = 0; ms < 2; ms++)
    for (int ns = 0; ns < 4; ns++){
      int mrow = m0 + wr * 32 + ms * 16 + lg * 4;
      int ncol;
      if constexpr (OUT == 3){
        int p = ((ns >> 1) << 5) | ((lr >> 2) << 3) | ((ns & 1) << 2) | (lr & 3);
        ncol = n0 + wc * 64 + p;
      } else {
        ncol = n0 + wc * 64 + ns * 16 + lr;
      }
      for (int rr = 0; rr < 4; rr++){
        float v = acc[ms][ns][rr];
        int o = (mrow + rr) * N + ncol;
        if constexpr (OUT == 2) ((float*)out0)[o] = v;
        else                    ((unsigned short*)out0)[o] = f2bf(v);
      }
    }
}

// ---------------------------------------------------------------------------
// Flash attention, swapped-operand (R9-exact). Grid 1024 qt-major,
// 4 waves x 16 q-rows, double-buffered K_hi/K_lo/V staging (48 KB).
// scores^T = mfma(A=K, B=Q); softmax in-lane + 4 shuffles; P^T in-register;
// V kappa-permuted at the V^T GEMM epilogue.
// Vt layout: [H][hd][B][S_kappa], addr = ((h*64+d)*4 + b)*1024 + s_phys.
__global__ __launch_bounds__(256) void k_attn(
    const unsigned short* __restrict__ Qh, const unsigned short* __restrict__ Ql,
    const unsigned short* __restrict__ Kh, const unsigned short* __restrict__ Kl,
    const unsigned short* __restrict__ Vt, unsigned short* __restrict__ Ob){
  __shared__ unsigned short s_k[2][12288];   // per buf: Kh 4096 | Kl 4096 | V 4096
  int tid = threadIdx.x;
  int w = tid >> 6, l = tid & 63, lg = l >> 4, lr = l & 15;
  int gx = blockIdx.x;
  int bh = gx & 63, qt = gx >> 6;
  int b = bh >> 4, h = bh & 15;
  int q0 = qt * 64;
  int qs = q0 + w * 16;
  int rowb = b * 1024;

  auto stage = [&](int kt, int bufi){
    int k0 = kt * 64;
    unsigned short* buf = s_k[bufi];
    for (int rep = 0; rep < 2; rep++){
      int idx = rep * 256 + tid;
      int r = idx >> 3, c = idx & 7;
      int cs = c ^ (r & 7);
      int srcK = (rowb + k0 + r) * 1024 + h * 64 + cs * 8;
      int srcV = ((h * 64 + r) * 4 + b) * 1024 + k0 + cs * 8;
      unsigned short* dst = buf + rep * 2048 + w * 512;
      gload16(Kh + srcK, dst);
      gload16(Kl + srcK, dst + 4096);
      gload16(Vt + srcV, dst + 8192);
    }
  };

  short8 fqh[2], fql[2];
  for (int ds = 0; ds < 2; ds++){
    int off = (rowb + qs + lr) * 1024 + h * 64 + ds * 32 + lg * 8;
    fqh[ds] = *(const short8*)(Qh + off);
    fql[ds] = *(const short8*)(Ql + off);
  }

  floatx4 oT[4] = {};      // O^T: col q = lr, row d = dsb*16 + 4*lg + rr
  float m_r = -__builtin_inff(), l_r = 0.f;   // per-lane q = qs + lr

  int ntile = qt + 1;
  stage(0, 0);
  __syncthreads();
  int cur = 0;
  for (int kt = 0; kt < ntile; kt++){
    int k0 = kt * 64;
    if (kt + 1 < ntile) stage(kt + 1, cur ^ 1);
    const unsigned short* kb = s_k[cur];

    floatx4 sc[4] = {};
    __builtin_amdgcn_s_setprio(1);
    for (int ds = 0; ds < 2; ds++)
      for (int s = 0; s < 4; s++){
        int r = s * 16 + lr;
        int off = r * 64 + (((ds * 4 + lg) ^ (r & 7)) * 8);
        short8 kh_f = *(const short8*)(kb + off);
        short8 kl_f = *(const short8*)(kb + 4096 + off);
        sc[s] = MFMA(kh_f, fqh[ds], sc[s], 0, 0, 0);
        sc[s] = MFMA(kl_f, fqh[ds], sc[s], 0, 0, 0);
        sc[s] = MFMA(kh_f, fql[ds], sc[s], 0, 0, 0);
      }
    __builtin_amdgcn_s_setprio(0);

    if (kt == ntile - 1){
      #pragma unroll
      for (int s = 0; s < 4; s++)
        #pragma unroll
        for (int rr = 0; rr < 4; rr++)
          if (k0 + s * 16 + 4 * lg + rr > qs + lr) sc[s][rr] = -__builtin_inff();
    }

    float mx = sc[0][0];
    #pragma unroll
    for (int s = 0; s < 4; s++)
      #pragma unroll
      for (int rr = 0; rr < 4; rr++) mx = fmaxf(mx, sc[s][rr]);
    mx = fmaxf(mx, __shfl_xor(mx, 16));
    mx = fmaxf(mx, __shfl_xor(mx, 32));
    float mn = fmaxf(m_r, mx);
    float fac = __expf(m_r - mn);
    m_r = mn;
    float ps = 0.f;
    #pragma unroll
    for (int s = 0; s < 4; s++)
      #pragma unroll
      for (int rr = 0; rr < 4; rr++){
        float p = __expf(sc[s][rr] - mn);
        sc[s][rr] = p;
        ps += p;
      }
    ps += __shfl_xor(ps, 16);
    ps += __shfl_xor(ps, 32);
    l_r = l_r * fac + ps;
    #pragma unroll
    for (int dsb = 0; dsb < 4; dsb++) oT[dsb] *= fac;

    __builtin_amdgcn_s_setprio(1);
    #pragma unroll
    for (int kk = 0; kk < 2; kk++){
      short8 pb;
      #pragma unroll
      for (int j = 0; j < 8; j++)
        pb[j] = (short)f2bf(sc[2 * kk + (j >> 2)][j & 3]);
      #pragma unroll
      for (int dsb = 0; dsb < 4; dsb++){
        int rv = dsb * 16 + lr;
        int offv = rv * 64 + (((kk * 4 + lg) ^ (rv & 7)) * 8);
        short8 vb = *(const short8*)(kb + 8192 + offv);
        oT[dsb] = MFMA(vb, pb, oT[dsb], 0, 0, 0);
      }
    }
    __builtin_amdgcn_s_setprio(0);
    __syncthreads();
    cur ^= 1;
  }

  float inv = 1.f / l_r;
  int base = (rowb + qs + lr) * 1024 + h * 64;
  #pragma unroll
  for (int dsb = 0; dsb < 4; dsb++){
    ushort4v o4;
    #pragma unroll
    for (int rr = 0; rr < 4; rr++) o4[rr] = f2bf(oT[dsb][rr] * inv);
    *(ushort4v*)(Ob + base + dsb * 16 + 4 * lg) = o4;
  }
}

// ---------------------------------------------------------------------------
extern "C" void kernel_launch(void* const* d_in, const int* in_sizes, int n_in,
                              void* d_out, int out_size, void* d_ws, size_t ws_size,
                              hipStream_t stream){
  const float* x  = (const float*)d_in[0];
  const float* Wq = (const float*)d_in[1];
  const float* Wk = (const float*)d_in[2];
  const float* Wv = (const float*)d_in[3];
  const float* Wo = (const float*)d_in[4];
  const float* fr = (const float*)d_in[5];
  const float* pr = (const float*)d_in[6];

  char* ws = (char*)d_ws;
  size_t off = 0;
  auto alloc = [&](size_t bytes) -> char* {
    char* p = ws + off;
    off += (bytes + 255) & ~(size_t)255;
    return p;
  };
  float* fw = (float*)alloc(1024 * sizeof(float));
  float* pw = (float*)alloc(256);
  const size_t WB = (size_t)1024 * 1024 * 2;
  unsigned short* wq_h = (unsigned short*)alloc(WB);
  unsigned short* wq_l = (unsigned short*)alloc(WB);
  unsigned short* wk_h = (unsigned short*)alloc(WB);
  unsigned short* wk_l = (unsigned short*)alloc(WB);
  unsigned short* wv_b = (unsigned short*)alloc(WB);
  unsigned short* wo_b = (unsigned short*)alloc(WB);
  const size_t XB = (size_t)4096 * 1024 * 2;
  unsigned short* x_h = (unsigned short*)alloc(XB);
  unsigned short* x_l = (unsigned short*)alloc(XB);
  unsigned short* q_h = (unsigned short*)alloc(XB);
  unsigned short* q_l = (unsigned short*)alloc(XB);
  unsigned short* k_h = (unsigned short*)alloc(XB);
  unsigned short* k_l = (unsigned short*)alloc(XB);
  unsigned short* vt  = (unsigned short*)alloc(XB);   // V^T [H*hd][B*S_kappa]
  unsigned short* o_b = x_l;   // alias: x_l dead after fused QK GEMM

  k_prep_fw<<<1, 1024, 0, stream>>>(fr, pr, fw, pw);
  k_prep_w<<<1024, 256, 0, stream>>>(Wq, Wk, Wv, Wo, fw, pw,
                                     wq_h, wq_l, wk_h, wk_l, wv_b, wo_b);
  k_split_x<<<4096, 256, 0, stream>>>(x, x_h, x_l);

  k_gemm_qk<<<512, 512, 0, stream>>>(x_h, x_l, wq_h, wq_l, wk_h, wk_l,
                                     q_h, q_l, k_h, k_l);
  // V^T = (x @ Wv^T)^T with kappa^-1 token scramble per 64-group
  dim3 ggv(32, 16);
  k_gemm<3><<<ggv, 256, 0, stream>>>(wv_b, x_h, (void*)vt, 1024, 4096, 1024);
  k_attn<<<1024, 256, 0, stream>>>(q_h, q_l, k_h, k_l, vt, o_b);
  dim3 ggo(8, 64);
  k_gemm<2><<<ggo, 256, 0, stream>>>(o_b, wo_b, d_out, 4096, 1024, 1024);
}